// Round 13
// baseline (575.007 us; speedup 1.0000x reference)
//
#include <hip/hip_runtime.h>
#include <stdint.h>

// Problem constants
constexpr int NB = 4;        // batch
constexpr int NT = 4096;     // time
constexpr int NH = 2048;     // hidden
constexpr int MROWS = NB * NT;       // 16384
constexpr int TP1 = NT + 1;          // 4097
constexpr int CH2 = 17;              // time-chunk for LSE scan (4097 = 17*241)
constexpr int NCH2 = 241;
constexpr int GSZ = 16;              // chunks per scan group
constexpr int NGRP = (NCH2 + GSZ - 1) / GSZ;   // 16
constexpr int NCOL = NB * NH;        // 8192 scan columns

typedef unsigned short u16;
typedef __bf16 bf16x8 __attribute__((ext_vector_type(8)));
typedef float f32x16 __attribute__((ext_vector_type(16)));
typedef float f32x4v __attribute__((ext_vector_type(4)));
typedef unsigned short u16x8 __attribute__((ext_vector_type(8)));
typedef _Float16 h16x8 __attribute__((ext_vector_type(8)));
typedef u16x8 __attribute__((may_alias)) u16x8_a;
typedef h16x8 __attribute__((may_alias)) h16x8_a;
typedef float4 __attribute__((may_alias)) float4_a;
typedef f32x4v __attribute__((may_alias)) f32x4v_a;

__device__ __forceinline__ u16 f2bf(float f) {
  unsigned int u = __float_as_uint(f);
  return (u16)((u + 0x7fffu + ((u >> 16) & 1u)) >> 16);
}
__device__ __forceinline__ float bf2f(u16 v) {
  return __uint_as_float(((unsigned int)v) << 16);
}
// fast softplus / g_log using native exp2-based intrinsics
__device__ __forceinline__ float spf_(float x) {
  return fmaxf(x, 0.f) + __logf(1.f + __expf(-fabsf(x)));
}
__device__ __forceinline__ float glogf_(float x) {       // g_log, G_EPS=0.5
  return (x >= 0.f) ? __logf(x + 0.5f) : -spf_(-x);
}
__device__ __forceinline__ void gld16(const void* g, void* l) {
  __builtin_amdgcn_global_load_lds((const __attribute__((address_space(1))) void*)g,
                                   (__attribute__((address_space(3))) void*)l, 16, 0, 0);
}
__device__ __forceinline__ void ld8(const float* p, float* r) {
  float4 a = *(const float4_a*)p, b = *(const float4_a*)(p + 4);
  r[0] = a.x; r[1] = a.y; r[2] = a.z; r[3] = a.w;
  r[4] = b.x; r[5] = b.y; r[6] = b.z; r[7] = b.w;
}
__device__ __forceinline__ void st8(float* p, const float* r) {
  *(float4_a*)p       = make_float4(r[0], r[1], r[2], r[3]);
  *(float4_a*)(p + 4) = make_float4(r[4], r[5], r[6], r[7]);
}
__device__ __forceinline__ void st8_nt(float* p, const float* r) {
  f32x4v a = {r[0], r[1], r[2], r[3]};
  f32x4v b = {r[4], r[5], r[6], r[7]};
  __builtin_nontemporal_store(a, (f32x4v_a*)p);
  __builtin_nontemporal_store(b, (f32x4v_a*)(p + 4));
}
// LSE-carry combine: (M,S) <- (M,S) (+) (Mo,So); commutative & associative.
__device__ __forceinline__ void lsecomb(float& M, float& S, float Mo, float So) {
  const float Mn = fmaxf(M, Mo);
  float Sn = S * __expf(M - Mn) + So * __expf(Mo - Mn);
  if (Mn == -INFINITY) Sn = 0.f;    // identity (+) identity guard
  M = Mn; S = Sn;
}

// ---------------- K0: fp32 -> bf16 convert, all three inputs ----------------
__global__ __launch_bounds__(256) void cvt_all(
    const float* __restrict__ hs, const float* __restrict__ Wz,
    const float* __restrict__ Wh, u16* __restrict__ hsb,
    u16* __restrict__ wzb, u16* __restrict__ whb) {
  const int s0 = MROWS * NH / 8;            // 4194304
  const int s1 = s0 + NH * NH / 8;          // +524288
  const int s2 = s1 + NH * NH / 8;
  int i = blockIdx.x * 256 + threadIdx.x;
  if (i >= s2) return;
  const float* in; u16* out; int j;
  if (i < s0)      { in = hs; out = hsb; j = i; }
  else if (i < s1) { in = Wz; out = wzb; j = i - s0; }
  else             { in = Wh; out = whb; j = i - s1; }
  const float4* p = (const float4*)in;
  float4 a = p[2 * (size_t)j], b = p[2 * (size_t)j + 1];
  u16x8 o;
  o[0] = f2bf(a.x); o[1] = f2bf(a.y); o[2] = f2bf(a.z); o[3] = f2bf(a.w);
  o[4] = f2bf(b.x); o[5] = f2bf(b.y); o[6] = f2bf(b.z); o[7] = f2bf(b.w);
  *(u16x8*)(out + (size_t)j * 8) = o;
}

// ---------------- K1: bf16 MFMA GEMM, 32x32x16 fragments --------------------
// 128x128 tile, BK=64, 4 waves (2Mx2N of 64x64; each 2x2 of 32x32 MFMA).
// Same LDS layout + T2 swizzle + T1 XCD swizzle as the proven 16x16 version.
// blockIdx.y=0: k -> KU[row*4096 + col]; =1: u -> KU[row*4096 + 2048 + col].
__global__ __launch_bounds__(256, 4) void gemm_bt32(
    const u16* __restrict__ A,
    const u16* __restrict__ Bz, const u16* __restrict__ Bh,
    const float* __restrict__ bz, const float* __restrict__ bh,
    u16* __restrict__ KU) {
  const u16* Bm  = blockIdx.y ? Bh : Bz;
  const float* bias = blockIdx.y ? bh : bz;
  u16* Cw = KU + (blockIdx.y ? 2048 : 0);

  // XCD-aware bijective swizzle: nwg(x) = 2048 = 8 * 256
  const int bid = blockIdx.x;
  const int wg = (bid & 7) * 256 + (bid >> 3);
  const int bx = wg & 15;           // N tile (16)
  const int by = wg >> 4;           // M tile (128)
  const int row0 = by << 7, col0 = bx << 7;

  __shared__ u16 ldsA[128 * 64];
  __shared__ u16 ldsB[128 * 64];

  const int tid = threadIdx.x;
  const int lane = tid & 63;
  const int wv = tid >> 6;
  const int wrow = (wv >> 1) << 6;   // wave row offset: 0 / 64
  const int wcol = (wv & 1) << 6;    // wave col offset: 0 / 64

  // staging lane geometry (8 rows x 8 16B-slots per wave-issue), T2 swizzle
  const int srow = lane >> 3;                       // row within 8-row segment
  const int sslot = ((lane & 7) ^ srow) << 3;       // swizzled source u16 col
  // read-side swizzle constants (32x32 fragment mapping)
  const int xsw = (lane & 7) << 3;                  // row&7 XOR mask
  const int kq8 = (lane >> 5) << 3;                 // k-group within K=16
  const int f31 = lane & 31;

  f32x16 acc[2][2] = {};

  for (int k0 = 0; k0 < NH; k0 += 64) {
    if (k0) __syncthreads();
#pragma unroll
    for (int i = 0; i < 4; ++i) {
      const int r = i * 32 + wv * 8 + srow;         // row within 128-row tile
      const size_t gcol = (size_t)(k0 + sslot);
      gld16(A  + (size_t)(row0 + r) * NH + gcol, &ldsA[(size_t)(i * 256 + wv * 64) * 8]);
      gld16(Bm + (size_t)(col0 + r) * NH + gcol, &ldsB[(size_t)(i * 256 + wv * 64) * 8]);
    }
    __syncthreads();
#pragma unroll
    for (int ks = 0; ks < 4; ++ks) {                // 4 x K=16 per BK=64
      const int cphys = ((ks << 4) | kq8) ^ xsw;    // physical u16 col
      bf16x8 af[2], bfr[2];
#pragma unroll
      for (int m = 0; m < 2; ++m)
        af[m] = *(const bf16x8*)&ldsA[(wrow + m * 32 + f31) * 64 + cphys];
#pragma unroll
      for (int n = 0; n < 2; ++n)
        bfr[n] = *(const bf16x8*)&ldsB[(wcol + n * 32 + f31) * 64 + cphys];
#pragma unroll
      for (int m = 0; m < 2; ++m)
#pragma unroll
        for (int n = 0; n < 2; ++n)
          acc[m][n] = __builtin_amdgcn_mfma_f32_32x32x16_bf16(af[m], bfr[n], acc[m][n], 0, 0, 0);
    }
  }

  // C/D mapping (verified m74/m101): col = lane&31, row = (r&3)+8*(r>>2)+4*(lane>>5)
  const int rhi = (lane >> 5) << 2;
#pragma unroll
  for (int n = 0; n < 2; ++n) {
    const int col = col0 + wcol + n * 32 + f31;
    const float bv = bias[col];
#pragma unroll
    for (int m = 0; m < 2; ++m) {
#pragma unroll
      for (int r = 0; r < 16; ++r) {
        const int row = row0 + wrow + m * 32 + (r & 3) + ((r >> 2) << 3) + rhi;
        Cw[(size_t)row * 4096 + col] = f2bf(acc[m][n][r] + bv);
      }
    }
  }
}

// ---- shared row-math for the scan passes: pointwise from bf16 k|u ----------
__device__ __forceinline__ void row_pointwise(const char* KU, size_t row,
                                              int tid, float* lc, float* lv) {
  const size_t rb = row * 8192;
  u16x8 kv = *(const u16x8_a*)(KU + rb + tid * 16);
  u16x8 uv = *(const u16x8_a*)(KU + rb + 4096 + tid * 16);
#pragma unroll
  for (int e = 0; e < 8; ++e) {
    const float k = bf2f(kv[e]);
    const float L = __logf(1.f + __expf(-fabsf(k)));
    lc[e] = -fmaxf(k, 0.f) - L;                      // log(1 - sigmoid(k))
    lv[e] = fminf(k, 0.f) - L + glogf_(bf2f(uv[e])); // log sig(k) + g_log(u)
  }
}

// ---------------- K2: pass 1 — per-chunk LSE carries only -------------------
__global__ __launch_bounds__(256) void carry_pass(
    const char* __restrict__ KU, float* __restrict__ cm, float* __restrict__ cs,
    const float* __restrict__ h0) {
  const int ch = blockIdx.x;
  const int b = blockIdx.y;
  const int tid = threadIdx.x;
  const int lane = tid & 63, wvx = tid >> 6;
  const int t0 = ch * CH2;
  const int t1 = (t0 + CH2 < TP1) ? (t0 + CH2) : TP1;

  float m8[8], s8[8];
#pragma unroll
  for (int e = 0; e < 8; ++e) { m8[e] = -INFINITY; s8[e] = 0.f; }

  __shared__ float wsum[2][4];

  float lc[8], lv[8];
  {
    const int tf = (t0 < 1) ? 1 : t0;
    if (tf < t1) row_pointwise(KU, (size_t)b * NT + (tf - 1), tid, lc, lv);
  }

  for (int tt = t0; tt < t1; ++tt) {
    if (tt == 0) {            // only chunk 0: x = g_log(h0), a_star = 0
#pragma unroll
      for (int e = 0; e < 8; ++e) {
        const float x = glogf_(h0[tid * 8 + e]);
        m8[e] = x; s8[e] = 1.f;
      }
      continue;
    }
    float nlc[8], nlv[8];
    const bool pf = (tt + 1 < t1);
    if (pf) row_pointwise(KU, (size_t)b * NT + tt, tid, nlc, nlv);

    // hidden-dim inclusive cumsum of lc across the 2048-wide row
    float cum[8], run = 0.f;
#pragma unroll
    for (int e = 0; e < 8; ++e) { run += lc[e]; cum[e] = run; }
    float v = run;
#pragma unroll
    for (int d = 1; d < 64; d <<= 1) {
      float o = __shfl_up(v, d, 64);
      if (lane >= d) v += o;
    }
    const int par = tt & 1;
    if (lane == 63) wsum[par][wvx] = v;
    __syncthreads();
    float base = v - run;
#pragma unroll
    for (int w = 0; w < 4; ++w)
      if (w < wvx) base += wsum[par][w];

#pragma unroll
    for (int e = 0; e < 8; ++e) {
      const float x = lv[e] - (base + cum[e]);
      const float nm = fmaxf(m8[e], x);
      s8[e] = s8[e] * __expf(m8[e] - nm) + __expf(x - nm);
      m8[e] = nm;
    }
    if (pf) {
#pragma unroll
      for (int e = 0; e < 8; ++e) { lc[e] = nlc[e]; lv[e] = nlv[e]; }
    }
  }
  const size_t co = ((size_t)ch * NB + b) * NH + tid * 8;
  st8(cm + co, m8);
  st8(cs + co, s8);
}

// ---------------- K3a: group-reduce chunk carries (coalesced) ---------------
__global__ __launch_bounds__(256) void carry_groupred(
    const float* __restrict__ cm, const float* __restrict__ cs,
    float* __restrict__ gm, float* __restrict__ gs) {
  const int c = blockIdx.x * 256 + threadIdx.x;
  const int g = blockIdx.y;
  const int ch0 = g * GSZ;
  const int ch1 = (ch0 + GSZ < NCH2) ? (ch0 + GSZ) : NCH2;
  float M = -INFINITY, S = 0.f;
  for (int ch = ch0; ch < ch1; ++ch) {
    const size_t o = (size_t)ch * NCOL + c;
    lsecomb(M, S, cm[o], cs[o]);
  }
  gm[(size_t)g * NCOL + c] = M;
  gs[(size_t)g * NCOL + c] = S;
}

// ---------------- K3b: exclusive scan over the NGRP group totals -----------
__global__ __launch_bounds__(256) void carry_groupscan(float* __restrict__ gm,
                                                       float* __restrict__ gs) {
  const int c = blockIdx.x * 256 + threadIdx.x;
  float M = -INFINITY, S = 0.f;
  for (int g = 0; g < NGRP; ++g) {
    const size_t o = (size_t)g * NCOL + c;
    const float m2 = gm[o], s2 = gs[o];
    gm[o] = M; gs[o] = S;
    lsecomb(M, S, m2, s2);
  }
}

// ---------------- K3c: apply group prefixes -> exclusive chunk prefixes ----
__global__ __launch_bounds__(256) void carry_apply(
    float* __restrict__ cm, float* __restrict__ cs,
    const float* __restrict__ gm, const float* __restrict__ gs) {
  const int c = blockIdx.x * 256 + threadIdx.x;
  const int g = blockIdx.y;
  const int ch0 = g * GSZ;
  const int ch1 = (ch0 + GSZ < NCH2) ? (ch0 + GSZ) : NCH2;
  float M = gm[(size_t)g * NCOL + c];
  float S = gs[(size_t)g * NCOL + c];
  for (int ch = ch0; ch < ch1; ++ch) {
    const size_t o = (size_t)ch * NCOL + c;
    const float m2 = cm[o], s2 = cs[o];
    cm[o] = M; cs[o] = S;
    lsecomb(M, S, m2, s2);
  }
}

// ---------------- K4: pass 2 — recompute + finish log_h + global stats -----
// Writes log_h as fp16 to LH16; accumulates sum/sumsq in doubles.
__global__ __launch_bounds__(256) void scan_final(
    const char* __restrict__ KU, _Float16* __restrict__ LH16,
    const float* __restrict__ cm, const float* __restrict__ cs,
    const float* __restrict__ h0, double* __restrict__ sums) {
  const int ch = blockIdx.x;
  const int b = blockIdx.y;
  const int tid = threadIdx.x;
  const int lane = tid & 63, wvx = tid >> 6;
  const int t0 = ch * CH2;
  const int t1 = (t0 + CH2 < TP1) ? (t0 + CH2) : TP1;

  float m8[8], s8[8];
  {
    const size_t co = ((size_t)ch * NB + b) * NH + tid * 8;
    ld8(cm + co, m8);
    ld8(cs + co, s8);
  }

  __shared__ float wsum[2][4];
  double s1 = 0.0, s2 = 0.0;

  float lc[8], lv[8];
  {
    const int tf = (t0 < 1) ? 1 : t0;
    if (tf < t1) row_pointwise(KU, (size_t)b * NT + (tf - 1), tid, lc, lv);
  }

  for (int tt = t0; tt < t1; ++tt) {
    if (tt == 0) {            // carry-in is (-inf,0) here; lh = g_log(h0)
#pragma unroll
      for (int e = 0; e < 8; ++e) {
        const float x = glogf_(h0[tid * 8 + e]);
        m8[e] = x; s8[e] = 1.f;
        s1 += (double)x;
        s2 += (double)x * (double)x;
      }
      continue;
    }
    float nlc[8], nlv[8];
    const bool pf = (tt + 1 < t1);
    if (pf) row_pointwise(KU, (size_t)b * NT + tt, tid, nlc, nlv);

    float cum[8], run = 0.f;
#pragma unroll
    for (int e = 0; e < 8; ++e) { run += lc[e]; cum[e] = run; }
    float v = run;
#pragma unroll
    for (int d = 1; d < 64; d <<= 1) {
      float o = __shfl_up(v, d, 64);
      if (lane >= d) v += o;
    }
    const int par = tt & 1;
    if (lane == 63) wsum[par][wvx] = v;
    __syncthreads();
    float base = v - run;
#pragma unroll
    for (int w = 0; w < 4; ++w)
      if (w < wvx) base += wsum[par][w];

    h16x8 lhv;
#pragma unroll
    for (int e = 0; e < 8; ++e) {
      const float as = base + cum[e];
      const float x = lv[e] - as;
      const float nm = fmaxf(m8[e], x);
      s8[e] = s8[e] * __expf(m8[e] - nm) + __expf(x - nm);
      m8[e] = nm;
      const float lh = as + nm + __logf(s8[e]);
      lhv[e] = (_Float16)lh;
      s1 += (double)lh;
      s2 += (double)lh * (double)lh;
    }
    const size_t row = (size_t)b * NT + (tt - 1);
    *(h16x8_a*)(LH16 + row * NH + tid * 8) = lhv;
    if (pf) {
#pragma unroll
      for (int e = 0; e < 8; ++e) { lc[e] = nlc[e]; lv[e] = nlv[e]; }
    }
  }
  // block reduce (doubles) -> device atomics
  double v1 = s1, v2 = s2;
#pragma unroll
  for (int d = 32; d; d >>= 1) {
    v1 += __shfl_down(v1, d, 64);
    v2 += __shfl_down(v2, d, 64);
  }
  __shared__ double dr1[4], dr2[4];
  if (lane == 0) { dr1[wvx] = v1; dr2[wvx] = v2; }
  __syncthreads();
  if (tid == 0) {
    atomicAdd(&sums[0], dr1[0] + dr1[1] + dr1[2] + dr1[3]);
    atomicAdd(&sums[1], dr2[0] + dr2[1] + dr2[2] + dr2[3]);
  }
}

// ---------------- K5: exp + residual(bf16) + LayerNorm (stats inline) -------
__global__ __launch_bounds__(256) void final_ln(
    float* __restrict__ OUT, const _Float16* __restrict__ LH16,
    const u16* __restrict__ hsb,
    const float* __restrict__ lnw, const float* __restrict__ lnb,
    const double* __restrict__ sums) {
  const int tid = threadIdx.x;
  const size_t off = (size_t)blockIdx.x * NH + tid * 8;

  __shared__ float sstat[2];
  if (tid == 0) {
    const double S = sums[0], S2 = sums[1];
    const double N = (double)NB * (double)TP1 * (double)NH;
    const double mu = S / N;
    const double var = (S2 - S * S / N) / (N - 1.0);
    sstat[0] = (float)mu;
    sstat[1] = (float)(1.0 / sqrt(var));
  }
  __syncthreads();
  const float mu_g = sstat[0], isd = sstat[1];

  float lh[8], av[8];
  {
    h16x8 hv = *(const h16x8_a*)(LH16 + off);
#pragma unroll
    for (int e = 0; e < 8; ++e) lh[e] = (float)hv[e];
  }
  {
    u16x8 hv = *(const u16x8_a*)(hsb + off);
#pragma unroll
    for (int e = 0; e < 8; ++e) av[e] = bf2f(hv[e]);
  }
  float x[8];
  float s = 0.f, q = 0.f;
#pragma unroll
  for (int e = 0; e < 8; ++e) {
    x[e] = __expf((lh[e] - mu_g) * isd) + av[e];
    s += x[e];
    q += x[e] * x[e];
  }
#pragma unroll
  for (int d = 32; d; d >>= 1) {
    s += __shfl_down(s, d, 64);
    q += __shfl_down(q, d, 64);
  }
  __shared__ float r1[4], r2[4];
  const int lane = tid & 63, wvx = tid >> 6;
  if (lane == 0) { r1[wvx] = s; r2[wvx] = q; }
  __syncthreads();
  const float st = r1[0] + r1[1] + r1[2] + r1[3];
  const float qt = r2[0] + r2[1] + r2[2] + r2[3];
  const float mean = st * (1.0f / NH);
  const float var = qt * (1.0f / NH) - mean * mean;
  const float rstd = rsqrtf(var + 1e-5f);

  float wv8[8], bv8[8];
  ld8(lnw + tid * 8, wv8);
  ld8(lnb + tid * 8, bv8);
  float o[8];
#pragma unroll
  for (int e = 0; e < 8; ++e)
    o[e] = (x[e] - mean) * rstd * wv8[e] + bv8[e];
  st8_nt(OUT + off, o);
}

extern "C" void kernel_launch(void* const* d_in, const int* in_sizes, int n_in,
                              void* d_out, int out_size, void* d_ws, size_t ws_size,
                              hipStream_t stream) {
  (void)in_sizes; (void)n_in; (void)out_size; (void)ws_size;
  const float* hs  = (const float*)d_in[0];
  const float* Wz  = (const float*)d_in[1];
  const float* bz  = (const float*)d_in[2];
  const float* Wh  = (const float*)d_in[3];
  const float* bh  = (const float*)d_in[4];
  const float* lnw = (const float*)d_in[5];
  const float* lnb = (const float*)d_in[6];
  const float* h0  = (const float*)d_in[7];
  float* out = (float*)d_out;

  // workspace carve (~210 MiB)
  char* w = (char*)d_ws;
  u16* hsb   = (u16*)w;  w += (size_t)MROWS * NH * 2;       // 64 MiB (live to end: residual)
  u16* wzb   = (u16*)w;  w += (size_t)NH * NH * 2;          // 8 MiB (dead after GEMM)
  u16* whb   = (u16*)w;  w += (size_t)NH * NH * 2;          // 8 MiB (dead after GEMM)
  char* KU   = w;        w += (size_t)MROWS * 8192;         // 128 MiB (k|u bf16)
  double* sums = (double*)w; w += 16;
  float* stats = (float*)w;  w += 64; (void)stats;
  float* gm_ = (float*)w;    w += (size_t)NGRP * NCOL * 4;  // 512 KiB
  float* gs_ = (float*)w;    w += (size_t)NGRP * NCOL * 4;  // 512 KiB
  _Float16* LH16 = (_Float16*)w; w += (size_t)MROWS * NH * 2; // 64 MiB
  // carries reuse wzb+whb (dead after GEMM): 2 x 7.9 MB <= 16 MiB
  float* cm_ = (float*)wzb;
  float* cs_ = cm_ + (size_t)NCH2 * NCOL;

  hipMemsetAsync(sums, 0, 16, stream);

  // K0: convert all fp32 inputs to bf16 (one launch)
  {
    const int tot8 = MROWS * NH / 8 + 2 * (NH * NH / 8);
    cvt_all<<<dim3((tot8 + 255) / 256), 256, 0, stream>>>(hs, Wz, Wh, hsb, wzb, whb);
  }

  // K1: k,u -> interleaved bf16 row-blocks in KU (32x32 MFMA)
  gemm_bt32<<<dim3((MROWS / 128) * (NH / 128), 2), 256, 0, stream>>>(
      hsb, wzb, whb, bz, bh, (u16*)KU);

  // K2: pass 1 — per-chunk carries
  carry_pass<<<dim3(NCH2, NB), 256, 0, stream>>>(KU, cm_, cs_, h0);

  // K3: hierarchical coalesced exclusive LSE scan of chunk carries
  carry_groupred<<<dim3(NCOL / 256, NGRP), 256, 0, stream>>>(cm_, cs_, gm_, gs_);
  carry_groupscan<<<dim3(NCOL / 256), 256, 0, stream>>>(gm_, gs_);
  carry_apply<<<dim3(NCOL / 256, NGRP), 256, 0, stream>>>(cm_, cs_, gm_, gs_);

  // K4: pass 2 — recompute + finish log_h (fp16) + global stats
  scan_final<<<dim3(NCH2, NB), 256, 0, stream>>>(KU, LH16, cm_, cs_, h0, sums);

  // K5: h = exp(norm(log_h)); x = h + hs(bf16); LayerNorm -> d_out
  final_ln<<<dim3(MROWS), 256, 0, stream>>>(out, LH16, hsb, lnw, lnb, sums);
}

// Round 14
// 536.435 us; speedup vs baseline: 1.0719x; 1.0719x over previous
//
#include <hip/hip_runtime.h>
#include <stdint.h>

// Problem constants
constexpr int NB = 4;        // batch
constexpr int NT = 4096;     // time
constexpr int NH = 2048;     // hidden
constexpr int MROWS = NB * NT;       // 16384
constexpr int TP1 = NT + 1;          // 4097
constexpr int CH2 = 17;              // time-chunk for LSE scan (4097 = 17*241)
constexpr int NCH2 = 241;
constexpr int GSZ = 16;              // chunks per scan group
constexpr int NGRP = (NCH2 + GSZ - 1) / GSZ;   // 16
constexpr int NCOL = NB * NH;        // 8192 scan columns

typedef unsigned short u16;
typedef __bf16 bf16x8 __attribute__((ext_vector_type(8)));
typedef float f32x4 __attribute__((ext_vector_type(4)));
typedef float f32x4v __attribute__((ext_vector_type(4)));
typedef unsigned short u16x8 __attribute__((ext_vector_type(8)));
typedef _Float16 h16x8 __attribute__((ext_vector_type(8)));
typedef u16x8 __attribute__((may_alias)) u16x8_a;
typedef h16x8 __attribute__((may_alias)) h16x8_a;
typedef float4 __attribute__((may_alias)) float4_a;
typedef f32x4v __attribute__((may_alias)) f32x4v_a;

__device__ __forceinline__ u16 f2bf(float f) {
  unsigned int u = __float_as_uint(f);
  return (u16)((u + 0x7fffu + ((u >> 16) & 1u)) >> 16);
}
__device__ __forceinline__ float bf2f(u16 v) {
  return __uint_as_float(((unsigned int)v) << 16);
}
// fast softplus / g_log using native exp2-based intrinsics
__device__ __forceinline__ float spf_(float x) {
  return fmaxf(x, 0.f) + __logf(1.f + __expf(-fabsf(x)));
}
__device__ __forceinline__ float glogf_(float x) {       // g_log, G_EPS=0.5
  return (x >= 0.f) ? __logf(x + 0.5f) : -spf_(-x);
}
__device__ __forceinline__ void gld16(const void* g, void* l) {
  __builtin_amdgcn_global_load_lds((const __attribute__((address_space(1))) void*)g,
                                   (__attribute__((address_space(3))) void*)l, 16, 0, 0);
}
__device__ __forceinline__ void ld8(const float* p, float* r) {
  float4 a = *(const float4_a*)p, b = *(const float4_a*)(p + 4);
  r[0] = a.x; r[1] = a.y; r[2] = a.z; r[3] = a.w;
  r[4] = b.x; r[5] = b.y; r[6] = b.z; r[7] = b.w;
}
__device__ __forceinline__ void st8(float* p, const float* r) {
  *(float4_a*)p       = make_float4(r[0], r[1], r[2], r[3]);
  *(float4_a*)(p + 4) = make_float4(r[4], r[5], r[6], r[7]);
}
__device__ __forceinline__ void st8_nt(float* p, const float* r) {
  f32x4v a = {r[0], r[1], r[2], r[3]};
  f32x4v b = {r[4], r[5], r[6], r[7]};
  __builtin_nontemporal_store(a, (f32x4v_a*)p);
  __builtin_nontemporal_store(b, (f32x4v_a*)(p + 4));
}
// LSE-carry combine: (M,S) <- (M,S) (+) (Mo,So); commutative & associative.
__device__ __forceinline__ void lsecomb(float& M, float& S, float Mo, float So) {
  const float Mn = fmaxf(M, Mo);
  float Sn = S * __expf(M - Mn) + So * __expf(Mo - Mn);
  if (Mn == -INFINITY) Sn = 0.f;    // identity (+) identity guard
  M = Mn; S = Sn;
}

// ---------------- K0: fp32 -> bf16 convert, all three inputs ----------------
__global__ __launch_bounds__(256) void cvt_all(
    const float* __restrict__ hs, const float* __restrict__ Wz,
    const float* __restrict__ Wh, u16* __restrict__ hsb,
    u16* __restrict__ wzb, u16* __restrict__ whb) {
  const int s0 = MROWS * NH / 8;            // 4194304
  const int s1 = s0 + NH * NH / 8;          // +524288
  const int s2 = s1 + NH * NH / 8;
  int i = blockIdx.x * 256 + threadIdx.x;
  if (i >= s2) return;
  const float* in; u16* out; int j;
  if (i < s0)      { in = hs; out = hsb; j = i; }
  else if (i < s1) { in = Wz; out = wzb; j = i - s0; }
  else             { in = Wh; out = whb; j = i - s1; }
  const float4* p = (const float4*)in;
  float4 a = p[2 * (size_t)j], b = p[2 * (size_t)j + 1];
  u16x8 o;
  o[0] = f2bf(a.x); o[1] = f2bf(a.y); o[2] = f2bf(a.z); o[3] = f2bf(a.w);
  o[4] = f2bf(b.x); o[5] = f2bf(b.y); o[6] = f2bf(b.z); o[7] = f2bf(b.w);
  *(u16x8*)(out + (size_t)j * 8) = o;
}

// ---------------- K1: bf16 MFMA GEMM (R11-proven 16x16, 4 waves/EU) ---------
// 128x128 tile, BK=64, 4 waves, T2 both-sides XOR swizzle, T1 XCD swizzle.
// blockIdx.y=0: k -> KU[row*4096 + col]; =1: u -> KU[row*4096 + 2048 + col].
__global__ __launch_bounds__(256, 4) void gemm_bt(
    const u16* __restrict__ A,
    const u16* __restrict__ Bz, const u16* __restrict__ Bh,
    const float* __restrict__ bz, const float* __restrict__ bh,
    u16* __restrict__ KU) {
  const u16* Bm  = blockIdx.y ? Bh : Bz;
  const float* bias = blockIdx.y ? bh : bz;
  u16* Cw = KU + (blockIdx.y ? 2048 : 0);

  // XCD-aware bijective swizzle: nwg(x) = 2048 = 8 * 256
  const int bid = blockIdx.x;
  const int wg = (bid & 7) * 256 + (bid >> 3);
  const int bx = wg & 15;           // N tile (16)
  const int by = wg >> 4;           // M tile (128)
  const int row0 = by << 7, col0 = bx << 7;

  __shared__ u16 ldsA[128 * 64];
  __shared__ u16 ldsB[128 * 64];

  const int tid = threadIdx.x;
  const int lane = tid & 63;
  const int wv = tid >> 6;
  const int wr = (wv >> 1) << 6;    // wave row offset: 0 / 64
  const int wc = (wv & 1) << 6;     // wave col offset: 0 / 64

  // staging lane geometry (8 rows x 8 16B-slots per wave-issue), T2 swizzle
  const int srow = lane >> 3;                       // row within 8-row segment
  const int sslot = ((lane & 7) ^ srow) << 3;       // swizzled source u16 col
  // read-side swizzle constants
  const int xsw = (lane & 7) << 3;
  const int q8 = (lane >> 4) << 3;
  const int f15 = lane & 15;

  f32x4 acc[4][4] = {};

  for (int k0 = 0; k0 < NH; k0 += 64) {
    if (k0) __syncthreads();
#pragma unroll
    for (int i = 0; i < 4; ++i) {
      const int r = i * 32 + wv * 8 + srow;         // row within 128-row tile
      const size_t gcol = (size_t)(k0 + sslot);
      gld16(A  + (size_t)(row0 + r) * NH + gcol, &ldsA[(size_t)(i * 256 + wv * 64) * 8]);
      gld16(Bm + (size_t)(col0 + r) * NH + gcol, &ldsB[(size_t)(i * 256 + wv * 64) * 8]);
    }
    __syncthreads();
#pragma unroll
    for (int ks = 0; ks < 2; ++ks) {
      const int cphys = ((ks << 5) | q8) ^ xsw;     // physical u16 col
      bf16x8 af[4], bfr[4];
#pragma unroll
      for (int m = 0; m < 4; ++m)
        af[m] = *(const bf16x8*)&ldsA[(wr + m * 16 + f15) * 64 + cphys];
#pragma unroll
      for (int n = 0; n < 4; ++n)
        bfr[n] = *(const bf16x8*)&ldsB[(wc + n * 16 + f15) * 64 + cphys];
#pragma unroll
      for (int m = 0; m < 4; ++m)
#pragma unroll
        for (int n = 0; n < 4; ++n)
          acc[m][n] = __builtin_amdgcn_mfma_f32_16x16x32_bf16(af[m], bfr[n], acc[m][n], 0, 0, 0);
    }
  }

  const int fr = lane & 15, fq = lane >> 4;
#pragma unroll
  for (int n = 0; n < 4; ++n) {
    const int col = col0 + wc + n * 16 + fr;
    const float bv = bias[col];
#pragma unroll
    for (int m = 0; m < 4; ++m) {
#pragma unroll
      for (int v = 0; v < 4; ++v) {
        const int row = row0 + wr + m * 16 + fq * 4 + v;
        Cw[(size_t)row * 4096 + col] = f2bf(acc[m][n][v] + bv);
      }
    }
  }
}

// ---- shared row-math for the scan passes: pointwise from bf16 k|u ----------
__device__ __forceinline__ void row_pointwise(const char* KU, size_t row,
                                              int tid, float* lc, float* lv) {
  const size_t rb = row * 8192;
  u16x8 kv = *(const u16x8_a*)(KU + rb + tid * 16);
  u16x8 uv = *(const u16x8_a*)(KU + rb + 4096 + tid * 16);
#pragma unroll
  for (int e = 0; e < 8; ++e) {
    const float k = bf2f(kv[e]);
    const float L = __logf(1.f + __expf(-fabsf(k)));
    lc[e] = -fmaxf(k, 0.f) - L;                      // log(1 - sigmoid(k))
    lv[e] = fminf(k, 0.f) - L + glogf_(bf2f(uv[e])); // log sig(k) + g_log(u)
  }
}

// ---------------- K2: pass 1 — per-chunk LSE carries only -------------------
__global__ __launch_bounds__(256) void carry_pass(
    const char* __restrict__ KU, float* __restrict__ cm, float* __restrict__ cs,
    const float* __restrict__ h0) {
  const int ch = blockIdx.x;
  const int b = blockIdx.y;
  const int tid = threadIdx.x;
  const int lane = tid & 63, wvx = tid >> 6;
  const int t0 = ch * CH2;
  const int t1 = (t0 + CH2 < TP1) ? (t0 + CH2) : TP1;

  float m8[8], s8[8];
#pragma unroll
  for (int e = 0; e < 8; ++e) { m8[e] = -INFINITY; s8[e] = 0.f; }

  __shared__ float wsum[2][4];

  float lc[8], lv[8];
  {
    const int tf = (t0 < 1) ? 1 : t0;
    if (tf < t1) row_pointwise(KU, (size_t)b * NT + (tf - 1), tid, lc, lv);
  }

  for (int tt = t0; tt < t1; ++tt) {
    if (tt == 0) {            // only chunk 0: x = g_log(h0), a_star = 0
#pragma unroll
      for (int e = 0; e < 8; ++e) {
        const float x = glogf_(h0[tid * 8 + e]);
        m8[e] = x; s8[e] = 1.f;
      }
      continue;
    }
    float nlc[8], nlv[8];
    const bool pf = (tt + 1 < t1);
    if (pf) row_pointwise(KU, (size_t)b * NT + tt, tid, nlc, nlv);

    // hidden-dim inclusive cumsum of lc across the 2048-wide row
    float cum[8], run = 0.f;
#pragma unroll
    for (int e = 0; e < 8; ++e) { run += lc[e]; cum[e] = run; }
    float v = run;
#pragma unroll
    for (int d = 1; d < 64; d <<= 1) {
      float o = __shfl_up(v, d, 64);
      if (lane >= d) v += o;
    }
    const int par = tt & 1;
    if (lane == 63) wsum[par][wvx] = v;
    __syncthreads();
    float base = v - run;
#pragma unroll
    for (int w = 0; w < 4; ++w)
      if (w < wvx) base += wsum[par][w];

#pragma unroll
    for (int e = 0; e < 8; ++e) {
      const float x = lv[e] - (base + cum[e]);
      const float nm = fmaxf(m8[e], x);
      s8[e] = s8[e] * __expf(m8[e] - nm) + __expf(x - nm);
      m8[e] = nm;
    }
    if (pf) {
#pragma unroll
      for (int e = 0; e < 8; ++e) { lc[e] = nlc[e]; lv[e] = nlv[e]; }
    }
  }
  const size_t co = ((size_t)ch * NB + b) * NH + tid * 8;
  st8(cm + co, m8);
  st8(cs + co, s8);
}

// ---------------- K3a: group-reduce chunk carries (coalesced) ---------------
// Writes INCLUSIVE group totals (not mutated afterwards).
__global__ __launch_bounds__(256) void carry_groupred(
    const float* __restrict__ cm, const float* __restrict__ cs,
    float* __restrict__ gm, float* __restrict__ gs) {
  const int c = blockIdx.x * 256 + threadIdx.x;
  const int g = blockIdx.y;
  const int ch0 = g * GSZ;
  const int ch1 = (ch0 + GSZ < NCH2) ? (ch0 + GSZ) : NCH2;
  float M = -INFINITY, S = 0.f;
  for (int ch = ch0; ch < ch1; ++ch) {
    const size_t o = (size_t)ch * NCOL + c;
    lsecomb(M, S, cm[o], cs[o]);
  }
  gm[(size_t)g * NCOL + c] = M;
  gs[(size_t)g * NCOL + c] = S;
}

// ---------------- K3b: apply — group prefix on the fly + chunk prefixes ----
// Block (bx, g): computes exclusive prefix over groups < g from totals
// (<= 15 lsecomb, ~7.7 MB total extra L2 reads), then rewrites its chunks
// in place with exclusive prefixes. Replaces the old groupscan kernel.
__global__ __launch_bounds__(256) void carry_apply(
    float* __restrict__ cm, float* __restrict__ cs,
    const float* __restrict__ gm, const float* __restrict__ gs) {
  const int c = blockIdx.x * 256 + threadIdx.x;
  const int g = blockIdx.y;
  const int ch0 = g * GSZ;
  const int ch1 = (ch0 + GSZ < NCH2) ? (ch0 + GSZ) : NCH2;
  float M = -INFINITY, S = 0.f;
  for (int gg = 0; gg < g; ++gg)
    lsecomb(M, S, gm[(size_t)gg * NCOL + c], gs[(size_t)gg * NCOL + c]);
  for (int ch = ch0; ch < ch1; ++ch) {
    const size_t o = (size_t)ch * NCOL + c;
    const float m2 = cm[o], s2 = cs[o];
    cm[o] = M; cs[o] = S;
    lsecomb(M, S, m2, s2);
  }
}

// ---------------- K4: pass 2 — recompute + finish log_h + global stats -----
// Writes log_h as fp16 to LH16; accumulates sum/sumsq in doubles.
__global__ __launch_bounds__(256) void scan_final(
    const char* __restrict__ KU, _Float16* __restrict__ LH16,
    const float* __restrict__ cm, const float* __restrict__ cs,
    const float* __restrict__ h0, double* __restrict__ sums) {
  const int ch = blockIdx.x;
  const int b = blockIdx.y;
  const int tid = threadIdx.x;
  const int lane = tid & 63, wvx = tid >> 6;
  const int t0 = ch * CH2;
  const int t1 = (t0 + CH2 < TP1) ? (t0 + CH2) : TP1;

  float m8[8], s8[8];
  {
    const size_t co = ((size_t)ch * NB + b) * NH + tid * 8;
    ld8(cm + co, m8);
    ld8(cs + co, s8);
  }

  __shared__ float wsum[2][4];
  double s1 = 0.0, s2 = 0.0;

  float lc[8], lv[8];
  {
    const int tf = (t0 < 1) ? 1 : t0;
    if (tf < t1) row_pointwise(KU, (size_t)b * NT + (tf - 1), tid, lc, lv);
  }

  for (int tt = t0; tt < t1; ++tt) {
    if (tt == 0) {            // carry-in is (-inf,0) here; lh = g_log(h0)
#pragma unroll
      for (int e = 0; e < 8; ++e) {
        const float x = glogf_(h0[tid * 8 + e]);
        m8[e] = x; s8[e] = 1.f;
        s1 += (double)x;
        s2 += (double)x * (double)x;
      }
      continue;
    }
    float nlc[8], nlv[8];
    const bool pf = (tt + 1 < t1);
    if (pf) row_pointwise(KU, (size_t)b * NT + tt, tid, nlc, nlv);

    float cum[8], run = 0.f;
#pragma unroll
    for (int e = 0; e < 8; ++e) { run += lc[e]; cum[e] = run; }
    float v = run;
#pragma unroll
    for (int d = 1; d < 64; d <<= 1) {
      float o = __shfl_up(v, d, 64);
      if (lane >= d) v += o;
    }
    const int par = tt & 1;
    if (lane == 63) wsum[par][wvx] = v;
    __syncthreads();
    float base = v - run;
#pragma unroll
    for (int w = 0; w < 4; ++w)
      if (w < wvx) base += wsum[par][w];

    h16x8 lhv;
#pragma unroll
    for (int e = 0; e < 8; ++e) {
      const float as = base + cum[e];
      const float x = lv[e] - as;
      const float nm = fmaxf(m8[e], x);
      s8[e] = s8[e] * __expf(m8[e] - nm) + __expf(x - nm);
      m8[e] = nm;
      const float lh = as + nm + __logf(s8[e]);
      lhv[e] = (_Float16)lh;
      s1 += (double)lh;
      s2 += (double)lh * (double)lh;
    }
    const size_t row = (size_t)b * NT + (tt - 1);
    *(h16x8_a*)(LH16 + row * NH + tid * 8) = lhv;
    if (pf) {
#pragma unroll
      for (int e = 0; e < 8; ++e) { lc[e] = nlc[e]; lv[e] = nlv[e]; }
    }
  }
  // block reduce (doubles) -> device atomics
  double v1 = s1, v2 = s2;
#pragma unroll
  for (int d = 32; d; d >>= 1) {
    v1 += __shfl_down(v1, d, 64);
    v2 += __shfl_down(v2, d, 64);
  }
  __shared__ double dr1[4], dr2[4];
  if (lane == 0) { dr1[wvx] = v1; dr2[wvx] = v2; }
  __syncthreads();
  if (tid == 0) {
    atomicAdd(&sums[0], dr1[0] + dr1[1] + dr1[2] + dr1[3]);
    atomicAdd(&sums[1], dr2[0] + dr2[1] + dr2[2] + dr2[3]);
  }
}

// ---------------- K5: exp + residual(bf16) + LayerNorm (stats inline) -------
__global__ __launch_bounds__(256) void final_ln(
    float* __restrict__ OUT, const _Float16* __restrict__ LH16,
    const u16* __restrict__ hsb,
    const float* __restrict__ lnw, const float* __restrict__ lnb,
    const double* __restrict__ sums) {
  const int tid = threadIdx.x;
  const size_t off = (size_t)blockIdx.x * NH + tid * 8;

  __shared__ float sstat[2];
  if (tid == 0) {
    const double S = sums[0], S2 = sums[1];
    const double N = (double)NB * (double)TP1 * (double)NH;
    const double mu = S / N;
    const double var = (S2 - S * S / N) / (N - 1.0);
    sstat[0] = (float)mu;
    sstat[1] = (float)(1.0 / sqrt(var));
  }
  __syncthreads();
  const float mu_g = sstat[0], isd = sstat[1];

  float lh[8], av[8];
  {
    h16x8 hv = *(const h16x8_a*)(LH16 + off);
#pragma unroll
    for (int e = 0; e < 8; ++e) lh[e] = (float)hv[e];
  }
  {
    u16x8 hv = *(const u16x8_a*)(hsb + off);
#pragma unroll
    for (int e = 0; e < 8; ++e) av[e] = bf2f(hv[e]);
  }
  float x[8];
  float s = 0.f, q = 0.f;
#pragma unroll
  for (int e = 0; e < 8; ++e) {
    x[e] = __expf((lh[e] - mu_g) * isd) + av[e];
    s += x[e];
    q += x[e] * x[e];
  }
#pragma unroll
  for (int d = 32; d; d >>= 1) {
    s += __shfl_down(s, d, 64);
    q += __shfl_down(q, d, 64);
  }
  __shared__ float r1[4], r2[4];
  const int lane = tid & 63, wvx = tid >> 6;
  if (lane == 0) { r1[wvx] = s; r2[wvx] = q; }
  __syncthreads();
  const float st = r1[0] + r1[1] + r1[2] + r1[3];
  const float qt = r2[0] + r2[1] + r2[2] + r2[3];
  const float mean = st * (1.0f / NH);
  const float var = qt * (1.0f / NH) - mean * mean;
  const float rstd = rsqrtf(var + 1e-5f);

  float wv8[8], bv8[8];
  ld8(lnw + tid * 8, wv8);
  ld8(lnb + tid * 8, bv8);
  float o[8];
#pragma unroll
  for (int e = 0; e < 8; ++e)
    o[e] = (x[e] - mean) * rstd * wv8[e] + bv8[e];
  st8_nt(OUT + off, o);
}

extern "C" void kernel_launch(void* const* d_in, const int* in_sizes, int n_in,
                              void* d_out, int out_size, void* d_ws, size_t ws_size,
                              hipStream_t stream) {
  (void)in_sizes; (void)n_in; (void)out_size; (void)ws_size;
  const float* hs  = (const float*)d_in[0];
  const float* Wz  = (const float*)d_in[1];
  const float* bz  = (const float*)d_in[2];
  const float* Wh  = (const float*)d_in[3];
  const float* bh  = (const float*)d_in[4];
  const float* lnw = (const float*)d_in[5];
  const float* lnb = (const float*)d_in[6];
  const float* h0  = (const float*)d_in[7];
  float* out = (float*)d_out;

  // workspace carve (~210 MiB)
  char* w = (char*)d_ws;
  u16* hsb   = (u16*)w;  w += (size_t)MROWS * NH * 2;       // 64 MiB (live to end: residual)
  u16* wzb   = (u16*)w;  w += (size_t)NH * NH * 2;          // 8 MiB (dead after GEMM)
  u16* whb   = (u16*)w;  w += (size_t)NH * NH * 2;          // 8 MiB (dead after GEMM)
  char* KU   = w;        w += (size_t)MROWS * 8192;         // 128 MiB (k|u bf16)
  double* sums = (double*)w; w += 16;
  float* gm_ = (float*)w;    w += (size_t)NGRP * NCOL * 4;  // 512 KiB
  float* gs_ = (float*)w;    w += (size_t)NGRP * NCOL * 4;  // 512 KiB
  _Float16* LH16 = (_Float16*)w; w += (size_t)MROWS * NH * 2; // 64 MiB
  // carries reuse wzb+whb (dead after GEMM): 2 x 7.9 MB <= 16 MiB
  float* cm_ = (float*)wzb;
  float* cs_ = cm_ + (size_t)NCH2 * NCOL;

  hipMemsetAsync(sums, 0, 16, stream);

  // K0: convert all fp32 inputs to bf16 (one launch)
  {
    const int tot8 = MROWS * NH / 8 + 2 * (NH * NH / 8);
    cvt_all<<<dim3((tot8 + 255) / 256), 256, 0, stream>>>(hs, Wz, Wh, hsb, wzb, whb);
  }

  // K1: k,u -> interleaved bf16 row-blocks in KU
  gemm_bt<<<dim3((MROWS / 128) * (NH / 128), 2), 256, 0, stream>>>(
      hsb, wzb, whb, bz, bh, (u16*)KU);

  // K2: pass 1 — per-chunk carries
  carry_pass<<<dim3(NCH2, NB), 256, 0, stream>>>(KU, cm_, cs_, h0);

  // K3: group totals, then apply (group prefix computed on the fly)
  carry_groupred<<<dim3(NCOL / 256, NGRP), 256, 0, stream>>>(cm_, cs_, gm_, gs_);
  carry_apply<<<dim3(NCOL / 256, NGRP), 256, 0, stream>>>(cm_, cs_, gm_, gs_);

  // K4: pass 2 — recompute + finish log_h (fp16) + global stats
  scan_final<<<dim3(NCH2, NB), 256, 0, stream>>>(KU, LH16, cm_, cs_, h0, sums);

  // K5: h = exp(norm(log_h)); x = h + hs(bf16); LayerNorm -> d_out
  final_ln<<<dim3(MROWS), 256, 0, stream>>>(out, LH16, hsb, lnw, lnb, sums);
}

// Round 15
// 536.092 us; speedup vs baseline: 1.0726x; 1.0006x over previous
//
#include <hip/hip_runtime.h>
#include <stdint.h>

// Problem constants
constexpr int NB = 4;        // batch
constexpr int NT = 4096;     // time
constexpr int NH = 2048;     // hidden
constexpr int MROWS = NB * NT;       // 16384
constexpr int TP1 = NT + 1;          // 4097
constexpr int CH2 = 17;              // time-chunk for LSE scan (4097 = 17*241)
constexpr int NCH2 = 241;
constexpr int GSZ = 16;              // chunks per scan group
constexpr int NGRP = (NCH2 + GSZ - 1) / GSZ;   // 16
constexpr int NCOL = NB * NH;        // 8192 scan columns

typedef unsigned short u16;
typedef __bf16 bf16x8 __attribute__((ext_vector_type(8)));
typedef float f32x4 __attribute__((ext_vector_type(4)));
typedef float f32x4v __attribute__((ext_vector_type(4)));
typedef unsigned short u16x8 __attribute__((ext_vector_type(8)));
typedef _Float16 h16x8 __attribute__((ext_vector_type(8)));
typedef u16x8 __attribute__((may_alias)) u16x8_a;
typedef h16x8 __attribute__((may_alias)) h16x8_a;
typedef float4 __attribute__((may_alias)) float4_a;
typedef f32x4v __attribute__((may_alias)) f32x4v_a;

__device__ __forceinline__ u16 f2bf(float f) {
  unsigned int u = __float_as_uint(f);
  return (u16)((u + 0x7fffu + ((u >> 16) & 1u)) >> 16);
}
__device__ __forceinline__ float bf2f(u16 v) {
  return __uint_as_float(((unsigned int)v) << 16);
}
// fast softplus / g_log using native exp2-based intrinsics
__device__ __forceinline__ float spf_(float x) {
  return fmaxf(x, 0.f) + __logf(1.f + __expf(-fabsf(x)));
}
__device__ __forceinline__ float glogf_(float x) {       // g_log, G_EPS=0.5
  return (x >= 0.f) ? __logf(x + 0.5f) : -spf_(-x);
}
__device__ __forceinline__ void gld16(const void* g, void* l) {
  __builtin_amdgcn_global_load_lds((const __attribute__((address_space(1))) void*)g,
                                   (__attribute__((address_space(3))) void*)l, 16, 0, 0);
}
__device__ __forceinline__ void ld8(const float* p, float* r) {
  float4 a = *(const float4_a*)p, b = *(const float4_a*)(p + 4);
  r[0] = a.x; r[1] = a.y; r[2] = a.z; r[3] = a.w;
  r[4] = b.x; r[5] = b.y; r[6] = b.z; r[7] = b.w;
}
__device__ __forceinline__ void st8(float* p, const float* r) {
  *(float4_a*)p       = make_float4(r[0], r[1], r[2], r[3]);
  *(float4_a*)(p + 4) = make_float4(r[4], r[5], r[6], r[7]);
}
__device__ __forceinline__ void st8_nt(float* p, const float* r) {
  f32x4v a = {r[0], r[1], r[2], r[3]};
  f32x4v b = {r[4], r[5], r[6], r[7]};
  __builtin_nontemporal_store(a, (f32x4v_a*)p);
  __builtin_nontemporal_store(b, (f32x4v_a*)(p + 4));
}
// LSE-carry combine: (M,S) <- (M,S) (+) (Mo,So); commutative & associative.
__device__ __forceinline__ void lsecomb(float& M, float& S, float Mo, float So) {
  const float Mn = fmaxf(M, Mo);
  float Sn = S * __expf(M - Mn) + So * __expf(Mo - Mn);
  if (Mn == -INFINITY) Sn = 0.f;    // identity (+) identity guard
  M = Mn; S = Sn;
}

// ---------------- K0: fp32 -> bf16 convert, all three inputs ----------------
__global__ __launch_bounds__(256) void cvt_all(
    const float* __restrict__ hs, const float* __restrict__ Wz,
    const float* __restrict__ Wh, u16* __restrict__ hsb,
    u16* __restrict__ wzb, u16* __restrict__ whb) {
  const int s0 = MROWS * NH / 8;            // 4194304
  const int s1 = s0 + NH * NH / 8;          // +524288
  const int s2 = s1 + NH * NH / 8;
  int i = blockIdx.x * 256 + threadIdx.x;
  if (i >= s2) return;
  const float* in; u16* out; int j;
  if (i < s0)      { in = hs; out = hsb; j = i; }
  else if (i < s1) { in = Wz; out = wzb; j = i - s0; }
  else             { in = Wh; out = whb; j = i - s1; }
  const float4* p = (const float4*)in;
  float4 a = p[2 * (size_t)j], b = p[2 * (size_t)j + 1];
  u16x8 o;
  o[0] = f2bf(a.x); o[1] = f2bf(a.y); o[2] = f2bf(a.z); o[3] = f2bf(a.w);
  o[4] = f2bf(b.x); o[5] = f2bf(b.y); o[6] = f2bf(b.z); o[7] = f2bf(b.w);
  *(u16x8*)(out + (size_t)j * 8) = o;
}

// ---------------- K1: bf16 MFMA GEMM (R11-proven 16x16, 4 waves/EU) ---------
// 128x128 tile, BK=64, 4 waves, T2 both-sides XOR swizzle, T1 XCD swizzle.
// blockIdx.y=0: k -> KU[row*4096 + col]; =1: u -> KU[row*4096 + 2048 + col].
__global__ __launch_bounds__(256, 4) void gemm_bt(
    const u16* __restrict__ A,
    const u16* __restrict__ Bz, const u16* __restrict__ Bh,
    const float* __restrict__ bz, const float* __restrict__ bh,
    u16* __restrict__ KU) {
  const u16* Bm  = blockIdx.y ? Bh : Bz;
  const float* bias = blockIdx.y ? bh : bz;
  u16* Cw = KU + (blockIdx.y ? 2048 : 0);

  // XCD-aware bijective swizzle: nwg(x) = 2048 = 8 * 256
  const int bid = blockIdx.x;
  const int wg = (bid & 7) * 256 + (bid >> 3);
  const int bx = wg & 15;           // N tile (16)
  const int by = wg >> 4;           // M tile (128)
  const int row0 = by << 7, col0 = bx << 7;

  __shared__ u16 ldsA[128 * 64];
  __shared__ u16 ldsB[128 * 64];

  const int tid = threadIdx.x;
  const int lane = tid & 63;
  const int wv = tid >> 6;
  const int wr = (wv >> 1) << 6;    // wave row offset: 0 / 64
  const int wc = (wv & 1) << 6;     // wave col offset: 0 / 64

  // staging lane geometry (8 rows x 8 16B-slots per wave-issue), T2 swizzle
  const int srow = lane >> 3;                       // row within 8-row segment
  const int sslot = ((lane & 7) ^ srow) << 3;       // swizzled source u16 col
  // read-side swizzle constants
  const int xsw = (lane & 7) << 3;
  const int q8 = (lane >> 4) << 3;
  const int f15 = lane & 15;

  f32x4 acc[4][4] = {};

  for (int k0 = 0; k0 < NH; k0 += 64) {
    if (k0) __syncthreads();
#pragma unroll
    for (int i = 0; i < 4; ++i) {
      const int r = i * 32 + wv * 8 + srow;         // row within 128-row tile
      const size_t gcol = (size_t)(k0 + sslot);
      gld16(A  + (size_t)(row0 + r) * NH + gcol, &ldsA[(size_t)(i * 256 + wv * 64) * 8]);
      gld16(Bm + (size_t)(col0 + r) * NH + gcol, &ldsB[(size_t)(i * 256 + wv * 64) * 8]);
    }
    __syncthreads();
#pragma unroll
    for (int ks = 0; ks < 2; ++ks) {
      const int cphys = ((ks << 5) | q8) ^ xsw;     // physical u16 col
      bf16x8 af[4], bfr[4];
#pragma unroll
      for (int m = 0; m < 4; ++m)
        af[m] = *(const bf16x8*)&ldsA[(wr + m * 16 + f15) * 64 + cphys];
#pragma unroll
      for (int n = 0; n < 4; ++n)
        bfr[n] = *(const bf16x8*)&ldsB[(wc + n * 16 + f15) * 64 + cphys];
#pragma unroll
      for (int m = 0; m < 4; ++m)
#pragma unroll
        for (int n = 0; n < 4; ++n)
          acc[m][n] = __builtin_amdgcn_mfma_f32_16x16x32_bf16(af[m], bfr[n], acc[m][n], 0, 0, 0);
    }
  }

  const int fr = lane & 15, fq = lane >> 4;
#pragma unroll
  for (int n = 0; n < 4; ++n) {
    const int col = col0 + wc + n * 16 + fr;
    const float bv = bias[col];
#pragma unroll
    for (int m = 0; m < 4; ++m) {
#pragma unroll
      for (int v = 0; v < 4; ++v) {
        const int row = row0 + wr + m * 16 + fq * 4 + v;
        Cw[(size_t)row * 4096 + col] = f2bf(acc[m][n][v] + bv);
      }
    }
  }
}

// ---- shared row-math for the scan passes: pointwise from bf16 k|u ----------
__device__ __forceinline__ void row_pointwise(const char* KU, size_t row,
                                              int tid, float* lc, float* lv) {
  const size_t rb = row * 8192;
  u16x8 kv = *(const u16x8_a*)(KU + rb + tid * 16);
  u16x8 uv = *(const u16x8_a*)(KU + rb + 4096 + tid * 16);
#pragma unroll
  for (int e = 0; e < 8; ++e) {
    const float k = bf2f(kv[e]);
    const float L = __logf(1.f + __expf(-fabsf(k)));
    lc[e] = -fmaxf(k, 0.f) - L;                      // log(1 - sigmoid(k))
    lv[e] = fminf(k, 0.f) - L + glogf_(bf2f(uv[e])); // log sig(k) + g_log(u)
  }
}

// ---------------- K2: pass 1 — per-chunk LSE carries only -------------------
__global__ __launch_bounds__(256) void carry_pass(
    const char* __restrict__ KU, float* __restrict__ cm, float* __restrict__ cs,
    const float* __restrict__ h0) {
  const int ch = blockIdx.x;
  const int b = blockIdx.y;
  const int tid = threadIdx.x;
  const int lane = tid & 63, wvx = tid >> 6;
  const int t0 = ch * CH2;
  const int t1 = (t0 + CH2 < TP1) ? (t0 + CH2) : TP1;

  float m8[8], s8[8];
#pragma unroll
  for (int e = 0; e < 8; ++e) { m8[e] = -INFINITY; s8[e] = 0.f; }

  __shared__ float wsum[2][4];

  float lc[8], lv[8];
  {
    const int tf = (t0 < 1) ? 1 : t0;
    if (tf < t1) row_pointwise(KU, (size_t)b * NT + (tf - 1), tid, lc, lv);
  }

  for (int tt = t0; tt < t1; ++tt) {
    if (tt == 0) {            // only chunk 0: x = g_log(h0), a_star = 0
#pragma unroll
      for (int e = 0; e < 8; ++e) {
        const float x = glogf_(h0[tid * 8 + e]);
        m8[e] = x; s8[e] = 1.f;
      }
      continue;
    }
    float nlc[8], nlv[8];
    const bool pf = (tt + 1 < t1);
    if (pf) row_pointwise(KU, (size_t)b * NT + tt, tid, nlc, nlv);

    // hidden-dim inclusive cumsum of lc across the 2048-wide row
    float cum[8], run = 0.f;
#pragma unroll
    for (int e = 0; e < 8; ++e) { run += lc[e]; cum[e] = run; }
    float v = run;
#pragma unroll
    for (int d = 1; d < 64; d <<= 1) {
      float o = __shfl_up(v, d, 64);
      if (lane >= d) v += o;
    }
    const int par = tt & 1;
    if (lane == 63) wsum[par][wvx] = v;
    __syncthreads();
    float base = v - run;
#pragma unroll
    for (int w = 0; w < 4; ++w)
      if (w < wvx) base += wsum[par][w];

#pragma unroll
    for (int e = 0; e < 8; ++e) {
      const float x = lv[e] - (base + cum[e]);
      const float nm = fmaxf(m8[e], x);
      s8[e] = s8[e] * __expf(m8[e] - nm) + __expf(x - nm);
      m8[e] = nm;
    }
    if (pf) {
#pragma unroll
      for (int e = 0; e < 8; ++e) { lc[e] = nlc[e]; lv[e] = nlv[e]; }
    }
  }
  const size_t co = ((size_t)ch * NB + b) * NH + tid * 8;
  st8(cm + co, m8);
  st8(cs + co, s8);
}

// ---------------- K3a: group-reduce chunk carries (coalesced) ---------------
// Writes INCLUSIVE group totals (not mutated afterwards).
__global__ __launch_bounds__(256) void carry_groupred(
    const float* __restrict__ cm, const float* __restrict__ cs,
    float* __restrict__ gm, float* __restrict__ gs) {
  const int c = blockIdx.x * 256 + threadIdx.x;
  const int g = blockIdx.y;
  const int ch0 = g * GSZ;
  const int ch1 = (ch0 + GSZ < NCH2) ? (ch0 + GSZ) : NCH2;
  float M = -INFINITY, S = 0.f;
  for (int ch = ch0; ch < ch1; ++ch) {
    const size_t o = (size_t)ch * NCOL + c;
    lsecomb(M, S, cm[o], cs[o]);
  }
  gm[(size_t)g * NCOL + c] = M;
  gs[(size_t)g * NCOL + c] = S;
}

// ---------------- K3b: apply — group prefix on the fly + chunk prefixes ----
// Block (bx, g): computes exclusive prefix over groups < g from totals
// (<= 15 lsecomb, ~7.7 MB total extra L2 reads), then rewrites its chunks
// in place with exclusive prefixes. Replaces the old groupscan kernel.
__global__ __launch_bounds__(256) void carry_apply(
    float* __restrict__ cm, float* __restrict__ cs,
    const float* __restrict__ gm, const float* __restrict__ gs) {
  const int c = blockIdx.x * 256 + threadIdx.x;
  const int g = blockIdx.y;
  const int ch0 = g * GSZ;
  const int ch1 = (ch0 + GSZ < NCH2) ? (ch0 + GSZ) : NCH2;
  float M = -INFINITY, S = 0.f;
  for (int gg = 0; gg < g; ++gg)
    lsecomb(M, S, gm[(size_t)gg * NCOL + c], gs[(size_t)gg * NCOL + c]);
  for (int ch = ch0; ch < ch1; ++ch) {
    const size_t o = (size_t)ch * NCOL + c;
    const float m2 = cm[o], s2 = cs[o];
    cm[o] = M; cs[o] = S;
    lsecomb(M, S, m2, s2);
  }
}

// ---------------- K4: pass 2 — recompute + finish log_h + global stats -----
// Writes log_h as fp16 to LH16; accumulates sum/sumsq in doubles.
__global__ __launch_bounds__(256) void scan_final(
    const char* __restrict__ KU, _Float16* __restrict__ LH16,
    const float* __restrict__ cm, const float* __restrict__ cs,
    const float* __restrict__ h0, double* __restrict__ sums) {
  const int ch = blockIdx.x;
  const int b = blockIdx.y;
  const int tid = threadIdx.x;
  const int lane = tid & 63, wvx = tid >> 6;
  const int t0 = ch * CH2;
  const int t1 = (t0 + CH2 < TP1) ? (t0 + CH2) : TP1;

  float m8[8], s8[8];
  {
    const size_t co = ((size_t)ch * NB + b) * NH + tid * 8;
    ld8(cm + co, m8);
    ld8(cs + co, s8);
  }

  __shared__ float wsum[2][4];
  double s1 = 0.0, s2 = 0.0;

  float lc[8], lv[8];
  {
    const int tf = (t0 < 1) ? 1 : t0;
    if (tf < t1) row_pointwise(KU, (size_t)b * NT + (tf - 1), tid, lc, lv);
  }

  for (int tt = t0; tt < t1; ++tt) {
    if (tt == 0) {            // carry-in is (-inf,0) here; lh = g_log(h0)
#pragma unroll
      for (int e = 0; e < 8; ++e) {
        const float x = glogf_(h0[tid * 8 + e]);
        m8[e] = x; s8[e] = 1.f;
        s1 += (double)x;
        s2 += (double)x * (double)x;
      }
      continue;
    }
    float nlc[8], nlv[8];
    const bool pf = (tt + 1 < t1);
    if (pf) row_pointwise(KU, (size_t)b * NT + tt, tid, nlc, nlv);

    float cum[8], run = 0.f;
#pragma unroll
    for (int e = 0; e < 8; ++e) { run += lc[e]; cum[e] = run; }
    float v = run;
#pragma unroll
    for (int d = 1; d < 64; d <<= 1) {
      float o = __shfl_up(v, d, 64);
      if (lane >= d) v += o;
    }
    const int par = tt & 1;
    if (lane == 63) wsum[par][wvx] = v;
    __syncthreads();
    float base = v - run;
#pragma unroll
    for (int w = 0; w < 4; ++w)
      if (w < wvx) base += wsum[par][w];

    h16x8 lhv;
#pragma unroll
    for (int e = 0; e < 8; ++e) {
      const float as = base + cum[e];
      const float x = lv[e] - as;
      const float nm = fmaxf(m8[e], x);
      s8[e] = s8[e] * __expf(m8[e] - nm) + __expf(x - nm);
      m8[e] = nm;
      const float lh = as + nm + __logf(s8[e]);
      lhv[e] = (_Float16)lh;
      s1 += (double)lh;
      s2 += (double)lh * (double)lh;
    }
    const size_t row = (size_t)b * NT + (tt - 1);
    *(h16x8_a*)(LH16 + row * NH + tid * 8) = lhv;
    if (pf) {
#pragma unroll
      for (int e = 0; e < 8; ++e) { lc[e] = nlc[e]; lv[e] = nlv[e]; }
    }
  }
  // block reduce (doubles) -> device atomics
  double v1 = s1, v2 = s2;
#pragma unroll
  for (int d = 32; d; d >>= 1) {
    v1 += __shfl_down(v1, d, 64);
    v2 += __shfl_down(v2, d, 64);
  }
  __shared__ double dr1[4], dr2[4];
  if (lane == 0) { dr1[wvx] = v1; dr2[wvx] = v2; }
  __syncthreads();
  if (tid == 0) {
    atomicAdd(&sums[0], dr1[0] + dr1[1] + dr1[2] + dr1[3]);
    atomicAdd(&sums[1], dr2[0] + dr2[1] + dr2[2] + dr2[3]);
  }
}

// ---------------- K5: exp + residual(bf16) + LayerNorm (stats inline) -------
__global__ __launch_bounds__(256) void final_ln(
    float* __restrict__ OUT, const _Float16* __restrict__ LH16,
    const u16* __restrict__ hsb,
    const float* __restrict__ lnw, const float* __restrict__ lnb,
    const double* __restrict__ sums) {
  const int tid = threadIdx.x;
  const size_t off = (size_t)blockIdx.x * NH + tid * 8;

  __shared__ float sstat[2];
  if (tid == 0) {
    const double S = sums[0], S2 = sums[1];
    const double N = (double)NB * (double)TP1 * (double)NH;
    const double mu = S / N;
    const double var = (S2 - S * S / N) / (N - 1.0);
    sstat[0] = (float)mu;
    sstat[1] = (float)(1.0 / sqrt(var));
  }
  __syncthreads();
  const float mu_g = sstat[0], isd = sstat[1];

  float lh[8], av[8];
  {
    h16x8 hv = *(const h16x8_a*)(LH16 + off);
#pragma unroll
    for (int e = 0; e < 8; ++e) lh[e] = (float)hv[e];
  }
  {
    u16x8 hv = *(const u16x8_a*)(hsb + off);
#pragma unroll
    for (int e = 0; e < 8; ++e) av[e] = bf2f(hv[e]);
  }
  float x[8];
  float s = 0.f, q = 0.f;
#pragma unroll
  for (int e = 0; e < 8; ++e) {
    x[e] = __expf((lh[e] - mu_g) * isd) + av[e];
    s += x[e];
    q += x[e] * x[e];
  }
#pragma unroll
  for (int d = 32; d; d >>= 1) {
    s += __shfl_down(s, d, 64);
    q += __shfl_down(q, d, 64);
  }
  __shared__ float r1[4], r2[4];
  const int lane = tid & 63, wvx = tid >> 6;
  if (lane == 0) { r1[wvx] = s; r2[wvx] = q; }
  __syncthreads();
  const float st = r1[0] + r1[1] + r1[2] + r1[3];
  const float qt = r2[0] + r2[1] + r2[2] + r2[3];
  const float mean = st * (1.0f / NH);
  const float var = qt * (1.0f / NH) - mean * mean;
  const float rstd = rsqrtf(var + 1e-5f);

  float wv8[8], bv8[8];
  ld8(lnw + tid * 8, wv8);
  ld8(lnb + tid * 8, bv8);
  float o[8];
#pragma unroll
  for (int e = 0; e < 8; ++e)
    o[e] = (x[e] - mean) * rstd * wv8[e] + bv8[e];
  st8_nt(OUT + off, o);
}

extern "C" void kernel_launch(void* const* d_in, const int* in_sizes, int n_in,
                              void* d_out, int out_size, void* d_ws, size_t ws_size,
                              hipStream_t stream) {
  (void)in_sizes; (void)n_in; (void)out_size; (void)ws_size;
  const float* hs  = (const float*)d_in[0];
  const float* Wz  = (const float*)d_in[1];
  const float* bz  = (const float*)d_in[2];
  const float* Wh  = (const float*)d_in[3];
  const float* bh  = (const float*)d_in[4];
  const float* lnw = (const float*)d_in[5];
  const float* lnb = (const float*)d_in[6];
  const float* h0  = (const float*)d_in[7];
  float* out = (float*)d_out;

  // workspace carve (~210 MiB)
  char* w = (char*)d_ws;
  u16* hsb   = (u16*)w;  w += (size_t)MROWS * NH * 2;       // 64 MiB (live to end: residual)
  u16* wzb   = (u16*)w;  w += (size_t)NH * NH * 2;          // 8 MiB (dead after GEMM)
  u16* whb   = (u16*)w;  w += (size_t)NH * NH * 2;          // 8 MiB (dead after GEMM)
  char* KU   = w;        w += (size_t)MROWS * 8192;         // 128 MiB (k|u bf16)
  double* sums = (double*)w; w += 16;
  float* gm_ = (float*)w;    w += (size_t)NGRP * NCOL * 4;  // 512 KiB
  float* gs_ = (float*)w;    w += (size_t)NGRP * NCOL * 4;  // 512 KiB
  _Float16* LH16 = (_Float16*)w; w += (size_t)MROWS * NH * 2; // 64 MiB
  // carries reuse wzb+whb (dead after GEMM): 2 x 7.9 MB <= 16 MiB
  float* cm_ = (float*)wzb;
  float* cs_ = cm_ + (size_t)NCH2 * NCOL;

  hipMemsetAsync(sums, 0, 16, stream);

  // K0: convert all fp32 inputs to bf16 (one launch)
  {
    const int tot8 = MROWS * NH / 8 + 2 * (NH * NH / 8);
    cvt_all<<<dim3((tot8 + 255) / 256), 256, 0, stream>>>(hs, Wz, Wh, hsb, wzb, whb);
  }

  // K1: k,u -> interleaved bf16 row-blocks in KU
  gemm_bt<<<dim3((MROWS / 128) * (NH / 128), 2), 256, 0, stream>>>(
      hsb, wzb, whb, bz, bh, (u16*)KU);

  // K2: pass 1 — per-chunk carries
  carry_pass<<<dim3(NCH2, NB), 256, 0, stream>>>(KU, cm_, cs_, h0);

  // K3: group totals, then apply (group prefix computed on the fly)
  carry_groupred<<<dim3(NCOL / 256, NGRP), 256, 0, stream>>>(cm_, cs_, gm_, gs_);
  carry_apply<<<dim3(NCOL / 256, NGRP), 256, 0, stream>>>(cm_, cs_, gm_, gs_);

  // K4: pass 2 — recompute + finish log_h (fp16) + global stats
  scan_final<<<dim3(NCH2, NB), 256, 0, stream>>>(KU, LH16, cm_, cs_, h0, sums);

  // K5: h = exp(norm(log_h)); x = h + hs(bf16); LayerNorm -> d_out
  final_ln<<<dim3(MROWS), 256, 0, stream>>>(out, LH16, hsb, lnw, lnb, sums);
}

// Round 16
// 535.173 us; speedup vs baseline: 1.0744x; 1.0017x over previous
//
#include <hip/hip_runtime.h>
#include <stdint.h>

// Problem constants
constexpr int NB = 4;        // batch
constexpr int NT = 4096;     // time
constexpr int NH = 2048;     // hidden
constexpr int MROWS = NB * NT;       // 16384
constexpr int TP1 = NT + 1;          // 4097
constexpr int GSZ = 16;              // chunks per scan group
constexpr int NCOL = NB * NH;        // 8192 scan columns
constexpr int CH_SMALL = 17;         // 241 chunks: cm/cs fit in dead wzb/whb
constexpr int CH_BIG = 8;            // 513 chunks: needs tail ws region

typedef unsigned short u16;
typedef __bf16 bf16x8 __attribute__((ext_vector_type(8)));
typedef float f32x4 __attribute__((ext_vector_type(4)));
typedef float f32x4v __attribute__((ext_vector_type(4)));
typedef unsigned short u16x8 __attribute__((ext_vector_type(8)));
typedef _Float16 h16x8 __attribute__((ext_vector_type(8)));
typedef u16x8 __attribute__((may_alias)) u16x8_a;
typedef h16x8 __attribute__((may_alias)) h16x8_a;
typedef float4 __attribute__((may_alias)) float4_a;
typedef f32x4v __attribute__((may_alias)) f32x4v_a;

__device__ __forceinline__ u16 f2bf(float f) {
  unsigned int u = __float_as_uint(f);
  return (u16)((u + 0x7fffu + ((u >> 16) & 1u)) >> 16);
}
__device__ __forceinline__ float bf2f(u16 v) {
  return __uint_as_float(((unsigned int)v) << 16);
}
// fast softplus / g_log using native exp2-based intrinsics
__device__ __forceinline__ float spf_(float x) {
  return fmaxf(x, 0.f) + __logf(1.f + __expf(-fabsf(x)));
}
__device__ __forceinline__ float glogf_(float x) {       // g_log, G_EPS=0.5
  return (x >= 0.f) ? __logf(x + 0.5f) : -spf_(-x);
}
__device__ __forceinline__ void gld16(const void* g, void* l) {
  __builtin_amdgcn_global_load_lds((const __attribute__((address_space(1))) void*)g,
                                   (__attribute__((address_space(3))) void*)l, 16, 0, 0);
}
__device__ __forceinline__ void ld8(const float* p, float* r) {
  float4 a = *(const float4_a*)p, b = *(const float4_a*)(p + 4);
  r[0] = a.x; r[1] = a.y; r[2] = a.z; r[3] = a.w;
  r[4] = b.x; r[5] = b.y; r[6] = b.z; r[7] = b.w;
}
__device__ __forceinline__ void st8(float* p, const float* r) {
  *(float4_a*)p       = make_float4(r[0], r[1], r[2], r[3]);
  *(float4_a*)(p + 4) = make_float4(r[4], r[5], r[6], r[7]);
}
__device__ __forceinline__ void st8_nt(float* p, const float* r) {
  f32x4v a = {r[0], r[1], r[2], r[3]};
  f32x4v b = {r[4], r[5], r[6], r[7]};
  __builtin_nontemporal_store(a, (f32x4v_a*)p);
  __builtin_nontemporal_store(b, (f32x4v_a*)(p + 4));
}
// LSE-carry combine: (M,S) <- (M,S) (+) (Mo,So); commutative & associative.
__device__ __forceinline__ void lsecomb(float& M, float& S, float Mo, float So) {
  const float Mn = fmaxf(M, Mo);
  float Sn = S * __expf(M - Mn) + So * __expf(Mo - Mn);
  if (Mn == -INFINITY) Sn = 0.f;    // identity (+) identity guard
  M = Mn; S = Sn;
}

// ---------------- K0: fp32 -> bf16 convert, all three inputs ----------------
__global__ __launch_bounds__(256) void cvt_all(
    const float* __restrict__ hs, const float* __restrict__ Wz,
    const float* __restrict__ Wh, u16* __restrict__ hsb,
    u16* __restrict__ wzb, u16* __restrict__ whb) {
  const int s0 = MROWS * NH / 8;            // 4194304
  const int s1 = s0 + NH * NH / 8;          // +524288
  const int s2 = s1 + NH * NH / 8;
  int i = blockIdx.x * 256 + threadIdx.x;
  if (i >= s2) return;
  const float* in; u16* out; int j;
  if (i < s0)      { in = hs; out = hsb; j = i; }
  else if (i < s1) { in = Wz; out = wzb; j = i - s0; }
  else             { in = Wh; out = whb; j = i - s1; }
  const float4* p = (const float4*)in;
  float4 a = p[2 * (size_t)j], b = p[2 * (size_t)j + 1];
  u16x8 o;
  o[0] = f2bf(a.x); o[1] = f2bf(a.y); o[2] = f2bf(a.z); o[3] = f2bf(a.w);
  o[4] = f2bf(b.x); o[5] = f2bf(b.y); o[6] = f2bf(b.z); o[7] = f2bf(b.w);
  *(u16x8*)(out + (size_t)j * 8) = o;
}

// ---------------- K1: bf16 MFMA GEMM (R11-proven 16x16, 4 waves/EU) ---------
// 128x128 tile, BK=64, 4 waves, T2 both-sides XOR swizzle, T1 XCD swizzle.
// blockIdx.y=0: k -> KU[row*4096 + col]; =1: u -> KU[row*4096 + 2048 + col].
__global__ __launch_bounds__(256, 4) void gemm_bt(
    const u16* __restrict__ A,
    const u16* __restrict__ Bz, const u16* __restrict__ Bh,
    const float* __restrict__ bz, const float* __restrict__ bh,
    u16* __restrict__ KU) {
  const u16* Bm  = blockIdx.y ? Bh : Bz;
  const float* bias = blockIdx.y ? bh : bz;
  u16* Cw = KU + (blockIdx.y ? 2048 : 0);

  // XCD-aware bijective swizzle: nwg(x) = 2048 = 8 * 256
  const int bid = blockIdx.x;
  const int wg = (bid & 7) * 256 + (bid >> 3);
  const int bx = wg & 15;           // N tile (16)
  const int by = wg >> 4;           // M tile (128)
  const int row0 = by << 7, col0 = bx << 7;

  __shared__ u16 ldsA[128 * 64];
  __shared__ u16 ldsB[128 * 64];

  const int tid = threadIdx.x;
  const int lane = tid & 63;
  const int wv = tid >> 6;
  const int wr = (wv >> 1) << 6;    // wave row offset: 0 / 64
  const int wc = (wv & 1) << 6;     // wave col offset: 0 / 64

  // staging lane geometry (8 rows x 8 16B-slots per wave-issue), T2 swizzle
  const int srow = lane >> 3;                       // row within 8-row segment
  const int sslot = ((lane & 7) ^ srow) << 3;       // swizzled source u16 col
  // read-side swizzle constants
  const int xsw = (lane & 7) << 3;
  const int q8 = (lane >> 4) << 3;
  const int f15 = lane & 15;

  f32x4 acc[4][4] = {};

  for (int k0 = 0; k0 < NH; k0 += 64) {
    if (k0) __syncthreads();
#pragma unroll
    for (int i = 0; i < 4; ++i) {
      const int r = i * 32 + wv * 8 + srow;         // row within 128-row tile
      const size_t gcol = (size_t)(k0 + sslot);
      gld16(A  + (size_t)(row0 + r) * NH + gcol, &ldsA[(size_t)(i * 256 + wv * 64) * 8]);
      gld16(Bm + (size_t)(col0 + r) * NH + gcol, &ldsB[(size_t)(i * 256 + wv * 64) * 8]);
    }
    __syncthreads();
#pragma unroll
    for (int ks = 0; ks < 2; ++ks) {
      const int cphys = ((ks << 5) | q8) ^ xsw;     // physical u16 col
      bf16x8 af[4], bfr[4];
#pragma unroll
      for (int m = 0; m < 4; ++m)
        af[m] = *(const bf16x8*)&ldsA[(wr + m * 16 + f15) * 64 + cphys];
#pragma unroll
      for (int n = 0; n < 4; ++n)
        bfr[n] = *(const bf16x8*)&ldsB[(wc + n * 16 + f15) * 64 + cphys];
#pragma unroll
      for (int m = 0; m < 4; ++m)
#pragma unroll
        for (int n = 0; n < 4; ++n)
          acc[m][n] = __builtin_amdgcn_mfma_f32_16x16x32_bf16(af[m], bfr[n], acc[m][n], 0, 0, 0);
    }
  }

  const int fr = lane & 15, fq = lane >> 4;
#pragma unroll
  for (int n = 0; n < 4; ++n) {
    const int col = col0 + wc + n * 16 + fr;
    const float bv = bias[col];
#pragma unroll
    for (int m = 0; m < 4; ++m) {
#pragma unroll
      for (int v = 0; v < 4; ++v) {
        const int row = row0 + wr + m * 16 + fq * 4 + v;
        Cw[(size_t)row * 4096 + col] = f2bf(acc[m][n][v] + bv);
      }
    }
  }
}

// ---- shared row-math for the scan passes: pointwise from bf16 k|u ----------
__device__ __forceinline__ void row_pointwise(const char* KU, size_t row,
                                              int tid, float* lc, float* lv) {
  const size_t rb = row * 8192;
  u16x8 kv = *(const u16x8_a*)(KU + rb + tid * 16);
  u16x8 uv = *(const u16x8_a*)(KU + rb + 4096 + tid * 16);
#pragma unroll
  for (int e = 0; e < 8; ++e) {
    const float k = bf2f(kv[e]);
    const float L = __logf(1.f + __expf(-fabsf(k)));
    lc[e] = -fmaxf(k, 0.f) - L;                      // log(1 - sigmoid(k))
    lv[e] = fminf(k, 0.f) - L + glogf_(bf2f(uv[e])); // log sig(k) + g_log(u)
  }
}

// ---------------- K2: pass 1 — per-chunk LSE carries only -------------------
template <int CHUNK>
__global__ __launch_bounds__(256) void carry_pass(
    const char* __restrict__ KU, float* __restrict__ cm, float* __restrict__ cs,
    const float* __restrict__ h0) {
  const int ch = blockIdx.x;
  const int b = blockIdx.y;
  const int tid = threadIdx.x;
  const int lane = tid & 63, wvx = tid >> 6;
  const int t0 = ch * CHUNK;
  const int t1 = (t0 + CHUNK < TP1) ? (t0 + CHUNK) : TP1;

  float m8[8], s8[8];
#pragma unroll
  for (int e = 0; e < 8; ++e) { m8[e] = -INFINITY; s8[e] = 0.f; }

  __shared__ float wsum[2][4];

  float lc[8], lv[8];
  {
    const int tf = (t0 < 1) ? 1 : t0;
    if (tf < t1) row_pointwise(KU, (size_t)b * NT + (tf - 1), tid, lc, lv);
  }

  for (int tt = t0; tt < t1; ++tt) {
    if (tt == 0) {            // only chunk 0: x = g_log(h0), a_star = 0
#pragma unroll
      for (int e = 0; e < 8; ++e) {
        const float x = glogf_(h0[tid * 8 + e]);
        m8[e] = x; s8[e] = 1.f;
      }
      continue;
    }
    float nlc[8], nlv[8];
    const bool pf = (tt + 1 < t1);
    if (pf) row_pointwise(KU, (size_t)b * NT + tt, tid, nlc, nlv);

    // hidden-dim inclusive cumsum of lc across the 2048-wide row
    float cum[8], run = 0.f;
#pragma unroll
    for (int e = 0; e < 8; ++e) { run += lc[e]; cum[e] = run; }
    float v = run;
#pragma unroll
    for (int d = 1; d < 64; d <<= 1) {
      float o = __shfl_up(v, d, 64);
      if (lane >= d) v += o;
    }
    const int par = tt & 1;
    if (lane == 63) wsum[par][wvx] = v;
    __syncthreads();
    float base = v - run;
#pragma unroll
    for (int w = 0; w < 4; ++w)
      if (w < wvx) base += wsum[par][w];

#pragma unroll
    for (int e = 0; e < 8; ++e) {
      const float x = lv[e] - (base + cum[e]);
      const float nm = fmaxf(m8[e], x);
      s8[e] = s8[e] * __expf(m8[e] - nm) + __expf(x - nm);
      m8[e] = nm;
    }
    if (pf) {
#pragma unroll
      for (int e = 0; e < 8; ++e) { lc[e] = nlc[e]; lv[e] = nlv[e]; }
    }
  }
  const size_t co = ((size_t)ch * NB + b) * NH + tid * 8;
  st8(cm + co, m8);
  st8(cs + co, s8);
}

// ---------------- K3a: group-reduce chunk carries (coalesced) ---------------
// Writes INCLUSIVE group totals (not mutated afterwards).
template <int CHUNK>
__global__ __launch_bounds__(256) void carry_groupred(
    const float* __restrict__ cm, const float* __restrict__ cs,
    float* __restrict__ gm, float* __restrict__ gs) {
  constexpr int NCHK = (TP1 + CHUNK - 1) / CHUNK;
  const int c = blockIdx.x * 256 + threadIdx.x;
  const int g = blockIdx.y;
  const int ch0 = g * GSZ;
  const int ch1 = (ch0 + GSZ < NCHK) ? (ch0 + GSZ) : NCHK;
  float M = -INFINITY, S = 0.f;
  for (int ch = ch0; ch < ch1; ++ch) {
    const size_t o = (size_t)ch * NCOL + c;
    lsecomb(M, S, cm[o], cs[o]);
  }
  gm[(size_t)g * NCOL + c] = M;
  gs[(size_t)g * NCOL + c] = S;
}

// ---------------- K3b: apply — group prefix on the fly + chunk prefixes ----
template <int CHUNK>
__global__ __launch_bounds__(256) void carry_apply(
    float* __restrict__ cm, float* __restrict__ cs,
    const float* __restrict__ gm, const float* __restrict__ gs) {
  constexpr int NCHK = (TP1 + CHUNK - 1) / CHUNK;
  const int c = blockIdx.x * 256 + threadIdx.x;
  const int g = blockIdx.y;
  const int ch0 = g * GSZ;
  const int ch1 = (ch0 + GSZ < NCHK) ? (ch0 + GSZ) : NCHK;
  float M = -INFINITY, S = 0.f;
  for (int gg = 0; gg < g; ++gg)
    lsecomb(M, S, gm[(size_t)gg * NCOL + c], gs[(size_t)gg * NCOL + c]);
  for (int ch = ch0; ch < ch1; ++ch) {
    const size_t o = (size_t)ch * NCOL + c;
    const float m2 = cm[o], s2 = cs[o];
    cm[o] = M; cs[o] = S;
    lsecomb(M, S, m2, s2);
  }
}

// ---------------- K4: pass 2 — recompute + finish log_h + global stats -----
// Writes log_h as fp16 to LH16; accumulates sum/sumsq in doubles.
template <int CHUNK>
__global__ __launch_bounds__(256) void scan_final(
    const char* __restrict__ KU, _Float16* __restrict__ LH16,
    const float* __restrict__ cm, const float* __restrict__ cs,
    const float* __restrict__ h0, double* __restrict__ sums) {
  const int ch = blockIdx.x;
  const int b = blockIdx.y;
  const int tid = threadIdx.x;
  const int lane = tid & 63, wvx = tid >> 6;
  const int t0 = ch * CHUNK;
  const int t1 = (t0 + CHUNK < TP1) ? (t0 + CHUNK) : TP1;

  float m8[8], s8[8];
  {
    const size_t co = ((size_t)ch * NB + b) * NH + tid * 8;
    ld8(cm + co, m8);
    ld8(cs + co, s8);
  }

  __shared__ float wsum[2][4];
  double s1 = 0.0, s2 = 0.0;

  float lc[8], lv[8];
  {
    const int tf = (t0 < 1) ? 1 : t0;
    if (tf < t1) row_pointwise(KU, (size_t)b * NT + (tf - 1), tid, lc, lv);
  }

  for (int tt = t0; tt < t1; ++tt) {
    if (tt == 0) {            // carry-in is (-inf,0) here; lh = g_log(h0)
#pragma unroll
      for (int e = 0; e < 8; ++e) {
        const float x = glogf_(h0[tid * 8 + e]);
        m8[e] = x; s8[e] = 1.f;
        s1 += (double)x;
        s2 += (double)x * (double)x;
      }
      continue;
    }
    float nlc[8], nlv[8];
    const bool pf = (tt + 1 < t1);
    if (pf) row_pointwise(KU, (size_t)b * NT + tt, tid, nlc, nlv);

    float cum[8], run = 0.f;
#pragma unroll
    for (int e = 0; e < 8; ++e) { run += lc[e]; cum[e] = run; }
    float v = run;
#pragma unroll
    for (int d = 1; d < 64; d <<= 1) {
      float o = __shfl_up(v, d, 64);
      if (lane >= d) v += o;
    }
    const int par = tt & 1;
    if (lane == 63) wsum[par][wvx] = v;
    __syncthreads();
    float base = v - run;
#pragma unroll
    for (int w = 0; w < 4; ++w)
      if (w < wvx) base += wsum[par][w];

    h16x8 lhv;
#pragma unroll
    for (int e = 0; e < 8; ++e) {
      const float as = base + cum[e];
      const float x = lv[e] - as;
      const float nm = fmaxf(m8[e], x);
      s8[e] = s8[e] * __expf(m8[e] - nm) + __expf(x - nm);
      m8[e] = nm;
      const float lh = as + nm + __logf(s8[e]);
      lhv[e] = (_Float16)lh;
      s1 += (double)lh;
      s2 += (double)lh * (double)lh;
    }
    const size_t row = (size_t)b * NT + (tt - 1);
    *(h16x8_a*)(LH16 + row * NH + tid * 8) = lhv;
    if (pf) {
#pragma unroll
      for (int e = 0; e < 8; ++e) { lc[e] = nlc[e]; lv[e] = nlv[e]; }
    }
  }
  // block reduce (doubles) -> device atomics
  double v1 = s1, v2 = s2;
#pragma unroll
  for (int d = 32; d; d >>= 1) {
    v1 += __shfl_down(v1, d, 64);
    v2 += __shfl_down(v2, d, 64);
  }
  __shared__ double dr1[4], dr2[4];
  if (lane == 0) { dr1[wvx] = v1; dr2[wvx] = v2; }
  __syncthreads();
  if (tid == 0) {
    atomicAdd(&sums[0], dr1[0] + dr1[1] + dr1[2] + dr1[3]);
    atomicAdd(&sums[1], dr2[0] + dr2[1] + dr2[2] + dr2[3]);
  }
}

// ---------------- K5: exp + residual(bf16) + LayerNorm (stats inline) -------
__global__ __launch_bounds__(256) void final_ln(
    float* __restrict__ OUT, const _Float16* __restrict__ LH16,
    const u16* __restrict__ hsb,
    const float* __restrict__ lnw, const float* __restrict__ lnb,
    const double* __restrict__ sums) {
  const int tid = threadIdx.x;
  const size_t off = (size_t)blockIdx.x * NH + tid * 8;

  __shared__ float sstat[2];
  if (tid == 0) {
    const double S = sums[0], S2 = sums[1];
    const double N = (double)NB * (double)TP1 * (double)NH;
    const double mu = S / N;
    const double var = (S2 - S * S / N) / (N - 1.0);
    sstat[0] = (float)mu;
    sstat[1] = (float)(1.0 / sqrt(var));
  }
  __syncthreads();
  const float mu_g = sstat[0], isd = sstat[1];

  float lh[8], av[8];
  {
    h16x8 hv = *(const h16x8_a*)(LH16 + off);
#pragma unroll
    for (int e = 0; e < 8; ++e) lh[e] = (float)hv[e];
  }
  {
    u16x8 hv = *(const u16x8_a*)(hsb + off);
#pragma unroll
    for (int e = 0; e < 8; ++e) av[e] = bf2f(hv[e]);
  }
  float x[8];
  float s = 0.f, q = 0.f;
#pragma unroll
  for (int e = 0; e < 8; ++e) {
    x[e] = __expf((lh[e] - mu_g) * isd) + av[e];
    s += x[e];
    q += x[e] * x[e];
  }
#pragma unroll
  for (int d = 32; d; d >>= 1) {
    s += __shfl_down(s, d, 64);
    q += __shfl_down(q, d, 64);
  }
  __shared__ float r1[4], r2[4];
  const int lane = tid & 63, wvx = tid >> 6;
  if (lane == 0) { r1[wvx] = s; r2[wvx] = q; }
  __syncthreads();
  const float st = r1[0] + r1[1] + r1[2] + r1[3];
  const float qt = r2[0] + r2[1] + r2[2] + r2[3];
  const float mean = st * (1.0f / NH);
  const float var = qt * (1.0f / NH) - mean * mean;
  const float rstd = rsqrtf(var + 1e-5f);

  float wv8[8], bv8[8];
  ld8(lnw + tid * 8, wv8);
  ld8(lnb + tid * 8, bv8);
  float o[8];
#pragma unroll
  for (int e = 0; e < 8; ++e)
    o[e] = (x[e] - mean) * rstd * wv8[e] + bv8[e];
  st8_nt(OUT + off, o);
}

// ---- templated scan-section driver -----------------------------------------
template <int CHUNK>
static void run_scan(const char* KU, _Float16* LH16, float* cm_, float* cs_,
                     float* gm_, float* gs_, const float* h0, double* sums,
                     hipStream_t stream) {
  constexpr int NCHK = (TP1 + CHUNK - 1) / CHUNK;
  constexpr int NGRPK = (NCHK + GSZ - 1) / GSZ;
  carry_pass<CHUNK><<<dim3(NCHK, NB), 256, 0, stream>>>(KU, cm_, cs_, h0);
  carry_groupred<CHUNK><<<dim3(NCOL / 256, NGRPK), 256, 0, stream>>>(cm_, cs_, gm_, gs_);
  carry_apply<CHUNK><<<dim3(NCOL / 256, NGRPK), 256, 0, stream>>>(cm_, cs_, gm_, gs_);
  scan_final<CHUNK><<<dim3(NCHK, NB), 256, 0, stream>>>(KU, LH16, cm_, cs_, h0, sums);
}

extern "C" void kernel_launch(void* const* d_in, const int* in_sizes, int n_in,
                              void* d_out, int out_size, void* d_ws, size_t ws_size,
                              hipStream_t stream) {
  (void)in_sizes; (void)n_in; (void)out_size;
  const float* hs  = (const float*)d_in[0];
  const float* Wz  = (const float*)d_in[1];
  const float* bz  = (const float*)d_in[2];
  const float* Wh  = (const float*)d_in[3];
  const float* bh  = (const float*)d_in[4];
  const float* lnw = (const float*)d_in[5];
  const float* lnb = (const float*)d_in[6];
  const float* h0  = (const float*)d_in[7];
  float* out = (float*)d_out;

  // workspace carve
  char* w0 = (char*)d_ws;
  char* w = w0;
  u16* hsb   = (u16*)w;  w += (size_t)MROWS * NH * 2;       // 64 MiB (live to end)
  u16* wzb   = (u16*)w;  w += (size_t)NH * NH * 2;          // 8 MiB (dead after GEMM)
  u16* whb   = (u16*)w;  w += (size_t)NH * NH * 2;          // 8 MiB (dead after GEMM)
  char* KU   = w;        w += (size_t)MROWS * 8192;         // 128 MiB (k|u bf16)
  double* sums = (double*)w; w += 64;
  float* gm_ = (float*)w;    w += (size_t)2 * 1024 * 1024;  // 2 MiB (NGRP<=33 -> 1.06 MiB)
  float* gs_ = (float*)w;    w += (size_t)2 * 1024 * 1024;  // 2 MiB
  _Float16* LH16 = (_Float16*)w; w += (size_t)MROWS * NH * 2; // 64 MiB
  // big carry region (CH_BIG=8 -> 513 chunks): 2 x 16.8 MB, gated on ws_size
  constexpr int NCH_BIG = (TP1 + CH_BIG - 1) / CH_BIG;      // 513
  float* cmB = (float*)w;
  float* csB = cmB + (size_t)NCH_BIG * NCOL;
  const size_t need_big = (size_t)(w - w0) + (size_t)2 * NCH_BIG * NCOL * 4;
  const bool big = (ws_size >= need_big);
  // small-path carries reuse wzb+whb (dead after GEMM): 2 x 7.9 MB <= 16 MiB
  float* cmS = (float*)wzb;
  float* csS = cmS + (size_t)((TP1 + CH_SMALL - 1) / CH_SMALL) * NCOL;

  hipMemsetAsync(sums, 0, 16, stream);

  // K0: convert all fp32 inputs to bf16 (one launch)
  {
    const int tot8 = MROWS * NH / 8 + 2 * (NH * NH / 8);
    cvt_all<<<dim3((tot8 + 255) / 256), 256, 0, stream>>>(hs, Wz, Wh, hsb, wzb, whb);
  }

  // K1: k,u -> interleaved bf16 row-blocks in KU
  gemm_bt<<<dim3((MROWS / 128) * (NH / 128), 2), 256, 0, stream>>>(
      hsb, wzb, whb, bz, bh, (u16*)KU);

  // K2..K4: chunked LSE scan (fine chunks if workspace allows)
  if (big)
    run_scan<CH_BIG>(KU, LH16, cmB, csB, gm_, gs_, h0, sums, stream);
  else
    run_scan<CH_SMALL>(KU, LH16, cmS, csS, gm_, gs_, h0, sums, stream);

  // K5: h = exp(norm(log_h)); x = h + hs(bf16); LayerNorm -> d_out
  final_ln<<<dim3(MROWS), 256, 0, stream>>>(out, LH16, hsb, lnw, lnb, sums);
}

// Round 17
// 520.544 us; speedup vs baseline: 1.1046x; 1.0281x over previous
//
#include <hip/hip_runtime.h>
#include <stdint.h>

// Problem constants
constexpr int NB = 4;        // batch
constexpr int NT = 4096;     // time
constexpr int NH = 2048;     // hidden
constexpr int MROWS = NB * NT;       // 16384
constexpr int TP1 = NT + 1;          // 4097
constexpr int GSZ = 16;              // chunks per scan group
constexpr int NCOL = NB * NH;        // 8192 scan columns
constexpr int CH_SMALL = 17;         // 241 chunks: cm/cs fit in dead wzb/whb
constexpr int CH_BIG = 8;            // 513 chunks: needs tail ws region

typedef unsigned short u16;
typedef __bf16 bf16x8 __attribute__((ext_vector_type(8)));
typedef float f32x4 __attribute__((ext_vector_type(4)));
typedef float f32x4v __attribute__((ext_vector_type(4)));
typedef unsigned short u16x8 __attribute__((ext_vector_type(8)));
typedef _Float16 h16x8 __attribute__((ext_vector_type(8)));
typedef u16x8 __attribute__((may_alias)) u16x8_a;
typedef h16x8 __attribute__((may_alias)) h16x8_a;
typedef float4 __attribute__((may_alias)) float4_a;
typedef f32x4v __attribute__((may_alias)) f32x4v_a;

__device__ __forceinline__ u16 f2bf(float f) {
  unsigned int u = __float_as_uint(f);
  return (u16)((u + 0x7fffu + ((u >> 16) & 1u)) >> 16);
}
__device__ __forceinline__ float bf2f(u16 v) {
  return __uint_as_float(((unsigned int)v) << 16);
}
// fast softplus / g_log using native exp2-based intrinsics
__device__ __forceinline__ float spf_(float x) {
  return fmaxf(x, 0.f) + __logf(1.f + __expf(-fabsf(x)));
}
__device__ __forceinline__ float glogf_(float x) {       // g_log, G_EPS=0.5
  return (x >= 0.f) ? __logf(x + 0.5f) : -spf_(-x);
}
__device__ __forceinline__ void gld16(const void* g, void* l) {
  __builtin_amdgcn_global_load_lds((const __attribute__((address_space(1))) void*)g,
                                   (__attribute__((address_space(3))) void*)l, 16, 0, 0);
}
__device__ __forceinline__ void ld8(const float* p, float* r) {
  float4 a = *(const float4_a*)p, b = *(const float4_a*)(p + 4);
  r[0] = a.x; r[1] = a.y; r[2] = a.z; r[3] = a.w;
  r[4] = b.x; r[5] = b.y; r[6] = b.z; r[7] = b.w;
}
__device__ __forceinline__ void st8(float* p, const float* r) {
  *(float4_a*)p       = make_float4(r[0], r[1], r[2], r[3]);
  *(float4_a*)(p + 4) = make_float4(r[4], r[5], r[6], r[7]);
}
__device__ __forceinline__ void st8_nt(float* p, const float* r) {
  f32x4v a = {r[0], r[1], r[2], r[3]};
  f32x4v b = {r[4], r[5], r[6], r[7]};
  __builtin_nontemporal_store(a, (f32x4v_a*)p);
  __builtin_nontemporal_store(b, (f32x4v_a*)(p + 4));
}
// LSE-carry combine: (M,S) <- (M,S) (+) (Mo,So); commutative & associative.
__device__ __forceinline__ void lsecomb(float& M, float& S, float Mo, float So) {
  const float Mn = fmaxf(M, Mo);
  float Sn = S * __expf(M - Mn) + So * __expf(Mo - Mn);
  if (Mn == -INFINITY) Sn = 0.f;    // identity (+) identity guard
  M = Mn; S = Sn;
}

// ---------------- K0: fp32 -> bf16 convert, all three inputs ----------------
__global__ __launch_bounds__(256) void cvt_all(
    const float* __restrict__ hs, const float* __restrict__ Wz,
    const float* __restrict__ Wh, u16* __restrict__ hsb,
    u16* __restrict__ wzb, u16* __restrict__ whb) {
  const int s0 = MROWS * NH / 8;            // 4194304
  const int s1 = s0 + NH * NH / 8;          // +524288
  const int s2 = s1 + NH * NH / 8;
  int i = blockIdx.x * 256 + threadIdx.x;
  if (i >= s2) return;
  const float* in; u16* out; int j;
  if (i < s0)      { in = hs; out = hsb; j = i; }
  else if (i < s1) { in = Wz; out = wzb; j = i - s0; }
  else             { in = Wh; out = whb; j = i - s1; }
  const float4* p = (const float4*)in;
  float4 a = p[2 * (size_t)j], b = p[2 * (size_t)j + 1];
  u16x8 o;
  o[0] = f2bf(a.x); o[1] = f2bf(a.y); o[2] = f2bf(a.z); o[3] = f2bf(a.w);
  o[4] = f2bf(b.x); o[5] = f2bf(b.y); o[6] = f2bf(b.z); o[7] = f2bf(b.w);
  *(u16x8*)(out + (size_t)j * 8) = o;
}

// ---------------- K1: bf16 MFMA GEMM (R11-proven 16x16, 4 waves/EU) ---------
// 128x128 tile, BK=64, 4 waves, T2 both-sides XOR swizzle, T1 XCD swizzle.
// blockIdx.y=0: k -> KU[row*4096 + col]; =1: u -> KU[row*4096 + 2048 + col].
__global__ __launch_bounds__(256, 4) void gemm_bt(
    const u16* __restrict__ A,
    const u16* __restrict__ Bz, const u16* __restrict__ Bh,
    const float* __restrict__ bz, const float* __restrict__ bh,
    u16* __restrict__ KU) {
  const u16* Bm  = blockIdx.y ? Bh : Bz;
  const float* bias = blockIdx.y ? bh : bz;
  u16* Cw = KU + (blockIdx.y ? 2048 : 0);

  // XCD-aware bijective swizzle: nwg(x) = 2048 = 8 * 256
  const int bid = blockIdx.x;
  const int wg = (bid & 7) * 256 + (bid >> 3);
  const int bx = wg & 15;           // N tile (16)
  const int by = wg >> 4;           // M tile (128)
  const int row0 = by << 7, col0 = bx << 7;

  __shared__ u16 ldsA[128 * 64];
  __shared__ u16 ldsB[128 * 64];

  const int tid = threadIdx.x;
  const int lane = tid & 63;
  const int wv = tid >> 6;
  const int wr = (wv >> 1) << 6;    // wave row offset: 0 / 64
  const int wc = (wv & 1) << 6;     // wave col offset: 0 / 64

  // staging lane geometry (8 rows x 8 16B-slots per wave-issue), T2 swizzle
  const int srow = lane >> 3;                       // row within 8-row segment
  const int sslot = ((lane & 7) ^ srow) << 3;       // swizzled source u16 col
  // read-side swizzle constants
  const int xsw = (lane & 7) << 3;
  const int q8 = (lane >> 4) << 3;
  const int f15 = lane & 15;

  f32x4 acc[4][4] = {};

  for (int k0 = 0; k0 < NH; k0 += 64) {
    if (k0) __syncthreads();
#pragma unroll
    for (int i = 0; i < 4; ++i) {
      const int r = i * 32 + wv * 8 + srow;         // row within 128-row tile
      const size_t gcol = (size_t)(k0 + sslot);
      gld16(A  + (size_t)(row0 + r) * NH + gcol, &ldsA[(size_t)(i * 256 + wv * 64) * 8]);
      gld16(Bm + (size_t)(col0 + r) * NH + gcol, &ldsB[(size_t)(i * 256 + wv * 64) * 8]);
    }
    __syncthreads();
#pragma unroll
    for (int ks = 0; ks < 2; ++ks) {
      const int cphys = ((ks << 5) | q8) ^ xsw;     // physical u16 col
      bf16x8 af[4], bfr[4];
#pragma unroll
      for (int m = 0; m < 4; ++m)
        af[m] = *(const bf16x8*)&ldsA[(wr + m * 16 + f15) * 64 + cphys];
#pragma unroll
      for (int n = 0; n < 4; ++n)
        bfr[n] = *(const bf16x8*)&ldsB[(wc + n * 16 + f15) * 64 + cphys];
#pragma unroll
      for (int m = 0; m < 4; ++m)
#pragma unroll
        for (int n = 0; n < 4; ++n)
          acc[m][n] = __builtin_amdgcn_mfma_f32_16x16x32_bf16(af[m], bfr[n], acc[m][n], 0, 0, 0);
    }
  }

  const int fr = lane & 15, fq = lane >> 4;
#pragma unroll
  for (int n = 0; n < 4; ++n) {
    const int col = col0 + wc + n * 16 + fr;
    const float bv = bias[col];
#pragma unroll
    for (int m = 0; m < 4; ++m) {
#pragma unroll
      for (int v = 0; v < 4; ++v) {
        const int row = row0 + wr + m * 16 + fq * 4 + v;
        Cw[(size_t)row * 4096 + col] = f2bf(acc[m][n][v] + bv);
      }
    }
  }
}

// ---- shared row-math for the scan passes: pointwise from bf16 k|u ----------
__device__ __forceinline__ void row_pointwise(const char* KU, size_t row,
                                              int tid, float* lc, float* lv) {
  const size_t rb = row * 8192;
  u16x8 kv = *(const u16x8_a*)(KU + rb + tid * 16);
  u16x8 uv = *(const u16x8_a*)(KU + rb + 4096 + tid * 16);
#pragma unroll
  for (int e = 0; e < 8; ++e) {
    const float k = bf2f(kv[e]);
    const float L = __logf(1.f + __expf(-fabsf(k)));
    lc[e] = -fmaxf(k, 0.f) - L;                      // log(1 - sigmoid(k))
    lv[e] = fminf(k, 0.f) - L + glogf_(bf2f(uv[e])); // log sig(k) + g_log(u)
  }
}

// ---------------- K2/K4 unified: chunked scan pass --------------------------
// FIN=0 (carry_pass): per-chunk (m,s) carries only; stores cm/cs at end.
// FIN=1 (scan_final): seeded by exclusive carry; writes log_h fp16 + stats.
// PAIR-ILP: two time-rows per iteration — independent hidden cumsums run
// with interleaved shuffle chains and ONE barrier per pair; the sequential
// per-column LSE update is applied in t-order afterwards (identical math).
template <int CHUNK, int FIN>
__global__ __launch_bounds__(256) void scan_pass(
    const char* __restrict__ KU, _Float16* __restrict__ LH16,
    float* __restrict__ cm, float* __restrict__ cs,
    const float* __restrict__ h0, double* __restrict__ sums) {
  const int ch = blockIdx.x;
  const int b = blockIdx.y;
  const int tid = threadIdx.x;
  const int lane = tid & 63, wvx = tid >> 6;
  const int t0 = ch * CHUNK;
  const int t1 = (t0 + CHUNK < TP1) ? (t0 + CHUNK) : TP1;

  float m8[8], s8[8];
  if (FIN) {
    const size_t co = ((size_t)ch * NB + b) * NH + tid * 8;
    ld8(cm + co, m8);
    ld8(cs + co, s8);
  } else {
#pragma unroll
    for (int e = 0; e < 8; ++e) { m8[e] = -INFINITY; s8[e] = 0.f; }
  }

  __shared__ float wsum[2][2][4];
  double s1 = 0.0, s2 = 0.0;

  int tt = t0;
  if (tt == 0) {              // uniform across block (only chunk 0)
#pragma unroll
    for (int e = 0; e < 8; ++e) {
      const float x = glogf_(h0[tid * 8 + e]);
      m8[e] = x; s8[e] = 1.f;
      if (FIN) { s1 += (double)x; s2 += (double)x * (double)x; }
    }
    tt = 1;
  }

  int par = 0;
  for (; tt + 1 < t1; tt += 2) {
    // rows tt and tt+1 (KU rows tt-1, tt) — loads issued together (2x MLP)
    float lcA[8], lvA[8], lcB[8], lvB[8];
    row_pointwise(KU, (size_t)b * NT + (tt - 1), tid, lcA, lvA);
    row_pointwise(KU, (size_t)b * NT + tt,       tid, lcB, lvB);

    // two independent hidden cumsums, shuffle chains interleaved (2x ILP)
    float cumA[8], cumB[8], runA = 0.f, runB = 0.f;
#pragma unroll
    for (int e = 0; e < 8; ++e) {
      runA += lcA[e]; cumA[e] = runA;
      runB += lcB[e]; cumB[e] = runB;
    }
    float vA = runA, vB = runB;
#pragma unroll
    for (int d = 1; d < 64; d <<= 1) {
      const float oA = __shfl_up(vA, d, 64);
      const float oB = __shfl_up(vB, d, 64);
      if (lane >= d) { vA += oA; vB += oB; }
    }
    if (lane == 63) { wsum[par][0][wvx] = vA; wsum[par][1][wvx] = vB; }
    __syncthreads();
    float baseA = vA - runA, baseB = vB - runB;
#pragma unroll
    for (int w = 0; w < 4; ++w)
      if (w < wvx) { baseA += wsum[par][0][w]; baseB += wsum[par][1][w]; }
    par ^= 1;

    // sequential LSE updates: row tt then row tt+1 (t-order preserved)
    h16x8 lhvA, lhvB;
#pragma unroll
    for (int e = 0; e < 8; ++e) {
      const float asA = baseA + cumA[e];
      const float xA = lvA[e] - asA;
      float nm = fmaxf(m8[e], xA);
      s8[e] = s8[e] * __expf(m8[e] - nm) + __expf(xA - nm);
      m8[e] = nm;
      if (FIN) {
        const float lh = asA + nm + __logf(s8[e]);
        lhvA[e] = (_Float16)lh;
        s1 += (double)lh; s2 += (double)lh * (double)lh;
      }
      const float asB = baseB + cumB[e];
      const float xB = lvB[e] - asB;
      nm = fmaxf(m8[e], xB);
      s8[e] = s8[e] * __expf(m8[e] - nm) + __expf(xB - nm);
      m8[e] = nm;
      if (FIN) {
        const float lh = asB + nm + __logf(s8[e]);
        lhvB[e] = (_Float16)lh;
        s1 += (double)lh; s2 += (double)lh * (double)lh;
      }
    }
    if (FIN) {
      *(h16x8_a*)(LH16 + ((size_t)b * NT + (tt - 1)) * NH + tid * 8) = lhvA;
      *(h16x8_a*)(LH16 + ((size_t)b * NT + tt) * NH + tid * 8)       = lhvB;
    }
  }

  if (tt < t1) {              // odd tail row
    float lc[8], lv[8];
    row_pointwise(KU, (size_t)b * NT + (tt - 1), tid, lc, lv);
    float cum[8], run = 0.f;
#pragma unroll
    for (int e = 0; e < 8; ++e) { run += lc[e]; cum[e] = run; }
    float v = run;
#pragma unroll
    for (int d = 1; d < 64; d <<= 1) {
      const float o = __shfl_up(v, d, 64);
      if (lane >= d) v += o;
    }
    if (lane == 63) wsum[par][0][wvx] = v;
    __syncthreads();
    float base = v - run;
#pragma unroll
    for (int w = 0; w < 4; ++w)
      if (w < wvx) base += wsum[par][0][w];
    h16x8 lhv;
#pragma unroll
    for (int e = 0; e < 8; ++e) {
      const float as = base + cum[e];
      const float x = lv[e] - as;
      const float nm = fmaxf(m8[e], x);
      s8[e] = s8[e] * __expf(m8[e] - nm) + __expf(x - nm);
      m8[e] = nm;
      if (FIN) {
        const float lh = as + nm + __logf(s8[e]);
        lhv[e] = (_Float16)lh;
        s1 += (double)lh; s2 += (double)lh * (double)lh;
      }
    }
    if (FIN)
      *(h16x8_a*)(LH16 + ((size_t)b * NT + (tt - 1)) * NH + tid * 8) = lhv;
  }

  if (!FIN) {
    const size_t co = ((size_t)ch * NB + b) * NH + tid * 8;
    st8(cm + co, m8);
    st8(cs + co, s8);
  } else {
    // block reduce (doubles) -> device atomics
    double v1 = s1, v2 = s2;
#pragma unroll
    for (int d = 32; d; d >>= 1) {
      v1 += __shfl_down(v1, d, 64);
      v2 += __shfl_down(v2, d, 64);
    }
    __shared__ double dr1[4], dr2[4];
    if (lane == 0) { dr1[wvx] = v1; dr2[wvx] = v2; }
    __syncthreads();
    if (tid == 0) {
      atomicAdd(&sums[0], dr1[0] + dr1[1] + dr1[2] + dr1[3]);
      atomicAdd(&sums[1], dr2[0] + dr2[1] + dr2[2] + dr2[3]);
    }
  }
}

// ---------------- K3a: group-reduce chunk carries (coalesced) ---------------
template <int CHUNK>
__global__ __launch_bounds__(256) void carry_groupred(
    const float* __restrict__ cm, const float* __restrict__ cs,
    float* __restrict__ gm, float* __restrict__ gs) {
  constexpr int NCHK = (TP1 + CHUNK - 1) / CHUNK;
  const int c = blockIdx.x * 256 + threadIdx.x;
  const int g = blockIdx.y;
  const int ch0 = g * GSZ;
  const int ch1 = (ch0 + GSZ < NCHK) ? (ch0 + GSZ) : NCHK;
  float M = -INFINITY, S = 0.f;
  for (int ch = ch0; ch < ch1; ++ch) {
    const size_t o = (size_t)ch * NCOL + c;
    lsecomb(M, S, cm[o], cs[o]);
  }
  gm[(size_t)g * NCOL + c] = M;
  gs[(size_t)g * NCOL + c] = S;
}

// ---------------- K3b: apply — group prefix on the fly + chunk prefixes ----
template <int CHUNK>
__global__ __launch_bounds__(256) void carry_apply(
    float* __restrict__ cm, float* __restrict__ cs,
    const float* __restrict__ gm, const float* __restrict__ gs) {
  constexpr int NCHK = (TP1 + CHUNK - 1) / CHUNK;
  const int c = blockIdx.x * 256 + threadIdx.x;
  const int g = blockIdx.y;
  const int ch0 = g * GSZ;
  const int ch1 = (ch0 + GSZ < NCHK) ? (ch0 + GSZ) : NCHK;
  float M = -INFINITY, S = 0.f;
  for (int gg = 0; gg < g; ++gg)
    lsecomb(M, S, gm[(size_t)gg * NCOL + c], gs[(size_t)gg * NCOL + c]);
  for (int ch = ch0; ch < ch1; ++ch) {
    const size_t o = (size_t)ch * NCOL + c;
    const float m2 = cm[o], s2 = cs[o];
    cm[o] = M; cs[o] = S;
    lsecomb(M, S, m2, s2);
  }
}

// ---------------- K5: exp + residual(bf16) + LayerNorm (stats inline) -------
__global__ __launch_bounds__(256) void final_ln(
    float* __restrict__ OUT, const _Float16* __restrict__ LH16,
    const u16* __restrict__ hsb,
    const float* __restrict__ lnw, const float* __restrict__ lnb,
    const double* __restrict__ sums) {
  const int tid = threadIdx.x;
  const size_t off = (size_t)blockIdx.x * NH + tid * 8;

  __shared__ float sstat[2];
  if (tid == 0) {
    const double S = sums[0], S2 = sums[1];
    const double N = (double)NB * (double)TP1 * (double)NH;
    const double mu = S / N;
    const double var = (S2 - S * S / N) / (N - 1.0);
    sstat[0] = (float)mu;
    sstat[1] = (float)(1.0 / sqrt(var));
  }
  __syncthreads();
  const float mu_g = sstat[0], isd = sstat[1];

  float lh[8], av[8];
  {
    h16x8 hv = *(const h16x8_a*)(LH16 + off);
#pragma unroll
    for (int e = 0; e < 8; ++e) lh[e] = (float)hv[e];
  }
  {
    u16x8 hv = *(const u16x8_a*)(hsb + off);
#pragma unroll
    for (int e = 0; e < 8; ++e) av[e] = bf2f(hv[e]);
  }
  float x[8];
  float s = 0.f, q = 0.f;
#pragma unroll
  for (int e = 0; e < 8; ++e) {
    x[e] = __expf((lh[e] - mu_g) * isd) + av[e];
    s += x[e];
    q += x[e] * x[e];
  }
#pragma unroll
  for (int d = 32; d; d >>= 1) {
    s += __shfl_down(s, d, 64);
    q += __shfl_down(q, d, 64);
  }
  __shared__ float r1[4], r2[4];
  const int lane = tid & 63, wvx = tid >> 6;
  if (lane == 0) { r1[wvx] = s; r2[wvx] = q; }
  __syncthreads();
  const float st = r1[0] + r1[1] + r1[2] + r1[3];
  const float qt = r2[0] + r2[1] + r2[2] + r2[3];
  const float mean = st * (1.0f / NH);
  const float var = qt * (1.0f / NH) - mean * mean;
  const float rstd = rsqrtf(var + 1e-5f);

  float wv8[8], bv8[8];
  ld8(lnw + tid * 8, wv8);
  ld8(lnb + tid * 8, bv8);
  float o[8];
#pragma unroll
  for (int e = 0; e < 8; ++e)
    o[e] = (x[e] - mean) * rstd * wv8[e] + bv8[e];
  st8_nt(OUT + off, o);
}

// ---- templated scan-section driver -----------------------------------------
template <int CHUNK>
static void run_scan(const char* KU, _Float16* LH16, float* cm_, float* cs_,
                     float* gm_, float* gs_, const float* h0, double* sums,
                     hipStream_t stream) {
  constexpr int NCHK = (TP1 + CHUNK - 1) / CHUNK;
  constexpr int NGRPK = (NCHK + GSZ - 1) / GSZ;
  scan_pass<CHUNK, 0><<<dim3(NCHK, NB), 256, 0, stream>>>(KU, nullptr, cm_, cs_, h0, sums);
  carry_groupred<CHUNK><<<dim3(NCOL / 256, NGRPK), 256, 0, stream>>>(cm_, cs_, gm_, gs_);
  carry_apply<CHUNK><<<dim3(NCOL / 256, NGRPK), 256, 0, stream>>>(cm_, cs_, gm_, gs_);
  scan_pass<CHUNK, 1><<<dim3(NCHK, NB), 256, 0, stream>>>(KU, LH16, cm_, cs_, h0, sums);
}

extern "C" void kernel_launch(void* const* d_in, const int* in_sizes, int n_in,
                              void* d_out, int out_size, void* d_ws, size_t ws_size,
                              hipStream_t stream) {
  (void)in_sizes; (void)n_in; (void)out_size;
  const float* hs  = (const float*)d_in[0];
  const float* Wz  = (const float*)d_in[1];
  const float* bz  = (const float*)d_in[2];
  const float* Wh  = (const float*)d_in[3];
  const float* bh  = (const float*)d_in[4];
  const float* lnw = (const float*)d_in[5];
  const float* lnb = (const float*)d_in[6];
  const float* h0  = (const float*)d_in[7];
  float* out = (float*)d_out;

  // workspace carve
  char* w0 = (char*)d_ws;
  char* w = w0;
  u16* hsb   = (u16*)w;  w += (size_t)MROWS * NH * 2;       // 64 MiB (live to end)
  u16* wzb   = (u16*)w;  w += (size_t)NH * NH * 2;          // 8 MiB (dead after GEMM)
  u16* whb   = (u16*)w;  w += (size_t)NH * NH * 2;          // 8 MiB (dead after GEMM)
  char* KU   = w;        w += (size_t)MROWS * 8192;         // 128 MiB (k|u bf16)
  double* sums = (double*)w; w += 64;
  float* gm_ = (float*)w;    w += (size_t)2 * 1024 * 1024;  // 2 MiB
  float* gs_ = (float*)w;    w += (size_t)2 * 1024 * 1024;  // 2 MiB
  _Float16* LH16 = (_Float16*)w; w += (size_t)MROWS * NH * 2; // 64 MiB
  // big carry region (CH_BIG=8 -> 513 chunks): 2 x 16.8 MB, gated on ws_size
  constexpr int NCH_BIG = (TP1 + CH_BIG - 1) / CH_BIG;      // 513
  float* cmB = (float*)w;
  float* csB = cmB + (size_t)NCH_BIG * NCOL;
  const size_t need_big = (size_t)(w - w0) + (size_t)2 * NCH_BIG * NCOL * 4;
  const bool big = (ws_size >= need_big);
  // small-path carries reuse wzb+whb (dead after GEMM): 2 x 7.9 MB <= 16 MiB
  float* cmS = (float*)wzb;
  float* csS = cmS + (size_t)((TP1 + CH_SMALL - 1) / CH_SMALL) * NCOL;

  hipMemsetAsync(sums, 0, 16, stream);

  // K0: convert all fp32 inputs to bf16 (one launch)
  {
    const int tot8 = MROWS * NH / 8 + 2 * (NH * NH / 8);
    cvt_all<<<dim3((tot8 + 255) / 256), 256, 0, stream>>>(hs, Wz, Wh, hsb, wzb, whb);
  }

  // K1: k,u -> interleaved bf16 row-blocks in KU
  gemm_bt<<<dim3((MROWS / 128) * (NH / 128), 2), 256, 0, stream>>>(
      hsb, wzb, whb, bz, bh, (u16*)KU);

  // K2..K4: chunked LSE scan (pair-row ILP; fine chunks if workspace allows)
  if (big)
    run_scan<CH_BIG>(KU, LH16, cmB, csB, gm_, gs_, h0, sums, stream);
  else
    run_scan<CH_SMALL>(KU, LH16, cmS, csS, gm_, gs_, h0, sums, stream);

  // K5: h = exp(norm(log_h)); x = h + hs(bf16); LayerNorm -> d_out
  final_ln<<<dim3(MROWS), 256, 0, stream>>>(out, LH16, hsb, lnw, lnb, sums);
}